// Round 12
// baseline (147.533 us; speedup 1.0000x reference)
//
#include <hip/hip_runtime.h>
#include <math.h>

#define B 8
#define C 64
#define CI 32
#define N 2304        // 48*48
#define NT 36         // tiles of 64
#define NTILES (B*NT) // 288
#define NTOT (B*N)    // 18432
#define BN_EPS 1e-5

// ---- workspace layout (float offsets) ----
#define OFF_GX   0                      // [B][N][CI] g_x
#define OFF_A    (OFF_GX + B*N*CI)      // [B][N]
#define OFF_C    (OFF_A + B*N)          // [B][N]
#define OFF_SC   (OFF_C + B*N)          // [B][N] sorted desc
#define OFF_SIDX (OFF_SC + B*N)         // [B][N] int
#define OFF_PLOC (OFF_SIDX + B*N)       // [B][N][64] excl. in-tile prefix (g | c*g)
#define OFF_TOT  (OFF_PLOC + B*N*64)    // [NTILES][64] tile totals
#define OFF_PART (OFF_TOT + NTILES*64)  // [NTILES][128] f32 per-tile partials
#define OFF_BAR  (OFF_PART + NTILES*128) // int[8*16]: barrier cells (memset 0 per call)

// ---- phase-overlaid LDS ----
struct SMemP1 { float gw[CI*C]; float tw[C]; float pw[C]; float gb[CI]; float tpb[2]; };
struct SMemP2 { __align__(16) unsigned long long keys[N]; int partial[256]; int partial2[256]; float av[64]; };
struct SMemP3 { float pl[64*64]; int sidx[64]; float scv[64]; float wtot[256]; float segoff[256]; };
struct SMemP4 { float offs[(NT+1)*64]; float y[64*33]; float Wl[C*CI]; float Wbl[C]; };
struct SMemP56 { double red[256]; float ss[128]; };
union SMem { SMemP1 p1; SMemP2 p2; SMemP3 p3; SMemP4 p4; SMemP56 p56; };

// grid barrier v2: 8 padded cells (blk&7) -> low RMW contention; RELAXED
// polling (no per-poll cache invalidate); one agent fence each side.
__device__ __forceinline__ void gbar(int* cells, int target) {
    __syncthreads();                         // block's stores issued
    if (threadIdx.x == 0) {
        __threadfence();                     // release: prior writes visible device-wide
        __hip_atomic_fetch_add(&cells[(blockIdx.x & 7) * 16], 1,
                               __ATOMIC_RELAXED, __HIP_MEMORY_SCOPE_AGENT);
        int sum = 0;
        #pragma unroll
        for (int i = 0; i < 8; i++)
            sum += __hip_atomic_load(&cells[i*16], __ATOMIC_RELAXED, __HIP_MEMORY_SCOPE_AGENT);
        while (sum < target) {
            __builtin_amdgcn_s_sleep(8);
            sum = 0;
            #pragma unroll
            for (int i = 0; i < 8; i++)
                sum += __hip_atomic_load(&cells[i*16], __ATOMIC_RELAXED, __HIP_MEMORY_SCOPE_AGENT);
        }
        __threadfence();                     // acquire: see all phase-i writes
    }
    __syncthreads();
}

// ------------------------------------------------------------------
__global__ __launch_bounds__(256) void k_mega(
    const float* __restrict__ x,
    const float* __restrict__ g_w, const float* __restrict__ g_b,
    const float* __restrict__ th_w, const float* __restrict__ th_b,
    const float* __restrict__ ph_w, const float* __restrict__ ph_b,
    const float* __restrict__ cp_wt, const float* __restrict__ cp_wp,
    const float* __restrict__ W_w, const float* __restrict__ W_b,
    const float* __restrict__ bn_g, const float* __restrict__ bn_b,
    float* __restrict__ ws, float* __restrict__ out)
{
    __shared__ SMem sm;
    int* bar = (int*)(ws + OFF_BAR);
    const int tid = threadIdx.x, blk = blockIdx.x;
    const int grid = (int)gridDim.x;
    const int p = tid & 63, wv = tid >> 6;
    const int t0 = blk;
    const int t1 = blk + grid;               // second tile-slot (persistent style)
    const bool has1 = (t1 < NTILES);

    float wy0[16], wy1[16];
    int   k0r = 0, k1r = 0;
    float a0r = 0.f, a1r = 0.f;

    //================ P1: projections ================
    {
        SMemP1& s = sm.p1;
        for (int i = tid; i < CI*C; i += 256) s.gw[i] = g_w[i];
        if (tid < C) {
            float acc = 0.f;
            for (int i = 0; i < CI; i++) acc += cp_wt[i] * th_w[i*C + tid];
            s.tw[tid] = acc;
        } else if (tid < 2*C) {
            int c = tid - C; float acc = 0.f;
            for (int i = 0; i < CI; i++) acc += cp_wp[i] * ph_w[i*C + c];
            s.pw[c] = acc;
        } else if (tid < 2*C + CI) {
            s.gb[tid - 2*C] = g_b[tid - 2*C];
        } else if (tid == 2*C + CI) {
            float acc = 0.f; for (int i = 0; i < CI; i++) acc += cp_wt[i]*th_b[i]; s.tpb[0] = acc;
        } else if (tid == 2*C + CI + 1) {
            float acc = 0.f; for (int i = 0; i < CI; i++) acc += cp_wp[i]*ph_b[i]; s.tpb[1] = acc;
        }
        __syncthreads();
        auto doP1 = [&](int t) {
            const int b = t / NT, n = (t % NT)*64 + p;
            const int ch0 = wv*8;
            const float* xb = x + (size_t)b*C*N + n;
            float accg[8];
            #pragma unroll
            for (int j = 0; j < 8; j++) accg[j] = 0.f;
            float aa = 0.f, cc = 0.f;
            #pragma unroll 4
            for (int c4 = 0; c4 < C; c4 += 4) {
                float xv0 = xb[(size_t)(c4+0)*N];          // coalesced over p
                float xv1 = xb[(size_t)(c4+1)*N];
                float xv2 = xb[(size_t)(c4+2)*N];
                float xv3 = xb[(size_t)(c4+3)*N];
                if (wv == 0) {                              // wave-uniform
                    float4 t4 = *(const float4*)(s.tw + c4);
                    aa += t4.x*xv0 + t4.y*xv1 + t4.z*xv2 + t4.w*xv3;
                } else if (wv == 1) {
                    float4 p4 = *(const float4*)(s.pw + c4);
                    cc += p4.x*xv0 + p4.y*xv1 + p4.z*xv2 + p4.w*xv3;
                }
                #pragma unroll
                for (int j = 0; j < 8; j++) {
                    float4 g4 = *(const float4*)(s.gw + (ch0+j)*C + c4);   // b128 bcast
                    accg[j] += g4.x*xv0 + g4.y*xv1 + g4.z*xv2 + g4.w*xv3;
                }
            }
            #pragma unroll
            for (int j = 0; j < 8; j++) accg[j] += s.gb[ch0 + j];
            float* gxp = ws + OFF_GX + ((size_t)(b*N + n))*CI + ch0;
            *(float4*)(gxp)     = make_float4(accg[0], accg[1], accg[2], accg[3]);
            *(float4*)(gxp + 4) = make_float4(accg[4], accg[5], accg[6], accg[7]);
            if (wv == 0) ws[OFF_A + b*N + n] = aa + s.tpb[0];
            else if (wv == 1) ws[OFF_C + b*N + n] = cc + s.tpb[1];
        };
        doP1(t0);
        if (has1) doP1(t1);
    }
    gbar(bar, grid);

    //================ P2: rank + k-count (u64 keys) ================
    // key = ord(c)<<12 | (4095-j): key_j > key_m <=> (c_j>c_m)||(c_j==c_m && j<m)
    // k(n) = #{key_j > ord(-a_n)<<12|4095} = #{c_j > -a_n} (boundary terms = 0)
    {
        auto doP2 = [&](int t, int& kr, float& ar) {
            SMemP2& s = sm.p2;
            const int b = t / NT, n0 = (t % NT)*64;
            const float* cb = ws + OFF_C + (size_t)b*N;
            for (int i = tid; i < N; i += 256) {
                unsigned int u = __float_as_uint(cb[i]);
                unsigned int k32 = (u & 0x80000000u) ? ~u : (u | 0x80000000u);
                s.keys[i] = ((unsigned long long)k32 << 12) | (unsigned long long)(4095 - i);
            }
            if (tid < 64) s.av[tid] = ws[OFF_A + b*N + n0 + tid];
            __syncthreads();
            const unsigned long long my = s.keys[n0 + p];
            unsigned int ua  = __float_as_uint(-s.av[p]);
            unsigned int t32 = (ua & 0x80000000u) ? ~ua : (ua | 0x80000000u);
            const unsigned long long thr = ((unsigned long long)t32 << 12) | 4095ull;
            const ulonglong2* kp = (const ulonglong2*)s.keys;
            int c0=0,c1=0,c2=0,c3=0, d0=0,d1=0,d2=0,d3=0;
            const int base = wv * (N/8);               // wave's j-quarter
            #pragma unroll 4
            for (int t2 = 0; t2 < N/8; t2 += 2) {
                ulonglong2 ka = kp[base + t2];
                ulonglong2 kb = kp[base + t2 + 1];
                c0 += (ka.x > my);  c1 += (ka.y > my);
                c2 += (kb.x > my);  c3 += (kb.y > my);
                d0 += (ka.x > thr); d1 += (ka.y > thr);
                d2 += (kb.x > thr); d3 += (kb.y > thr);
            }
            s.partial[tid]  = (c0 + c1) + (c2 + c3);
            s.partial2[tid] = (d0 + d1) + (d2 + d3);
            __syncthreads();
            kr = s.partial2[p] + s.partial2[p+64] + s.partial2[p+128] + s.partial2[p+192];
            ar = s.av[p];
            if (tid < 64) {
                int rank = s.partial[tid] + s.partial[tid+64] + s.partial[tid+128] + s.partial[tid+192];
                unsigned long long km = s.keys[n0 + tid];
                unsigned int k32 = (unsigned int)(km >> 12);
                unsigned int u = (k32 & 0x80000000u) ? (k32 & 0x7fffffffu) : ~k32;
                ws[OFF_SC + b*N + rank] = __uint_as_float(u);
                ((int*)(ws + OFF_SIDX))[b*N + rank] = n0 + tid;
            }
            __syncthreads();
        };
        doP2(t0, k0r, a0r);
        if (has1) doP2(t1, k1r, a1r);
    }
    gbar(bar, 2*grid);

    //================ P3: per-tile exclusive prefix (two-level) ================
    {
        auto doP3 = [&](int t) {
            SMemP3& s = sm.p3;
            const int b = t / NT, k0 = (t % NT)*64;
            if (tid < 64) {
                s.sidx[tid] = ((const int*)(ws + OFF_SIDX))[b*N + k0 + tid];
                s.scv[tid]  = ws[OFF_SC + b*N + k0 + tid];
            }
            __syncthreads();
            const int ch = tid & 63, chm = ch & 31;
            const bool isCG = ch >= 32;
            const float* gx = ws + OFF_GX + (size_t)b*N*CI;
            float acc = 0.f;
            #pragma unroll
            for (int kk = 0; kk < 16; kk++) {
                int k = wv*16 + kk;
                int m = s.sidx[k];                             // wave-uniform
                float gval = gx[(size_t)m*CI + chm];           // 128B gather
                float v = isCG ? gval * s.scv[k] : gval;
                s.pl[k*64 + ch] = acc;
                acc += v;
            }
            s.wtot[wv*64 + ch] = acc;
            __syncthreads();
            if (tid < 64) {
                float tt = 0.f;
                #pragma unroll
                for (int ww = 0; ww < 4; ww++) { s.segoff[ww*64 + tid] = tt; tt += s.wtot[ww*64 + tid]; }
                ws[OFF_TOT + (size_t)t*64 + tid] = tt;         // tile total
            }
            __syncthreads();
            float* pl = ws + OFF_PLOC + ((size_t)b*N + k0)*64;
            #pragma unroll
            for (int r4 = 0; r4 < 16; r4++) {
                int r = wv + r4*4;
                pl[(size_t)r*64 + ch] = s.pl[r*64 + ch] + s.segoff[(r >> 4)*64 + ch];
            }
            __syncthreads();
        };
        doP3(t0);
        if (has1) doP3(t1);
    }
    gbar(bar, 3*grid);

    //================ P4: y + wy (registers) + BN partials ================
    {
        SMemP4& s = sm.p4;
        for (int i = tid; i < C*CI; i += 256) s.Wl[i] = W_w[i];
        if (tid < C) s.Wbl[tid] = W_b[tid];
        auto doP4 = [&](int t, int kk, float an, float (&wyv)[16]) {
            const int b = t / NT, n = (t % NT)*64 + p;
            const float* tot = ws + OFF_TOT + (size_t)b*NT*64;
            for (int i = tid; i < NT*64; i += 256) s.offs[i] = tot[i];
            __syncthreads();
            if (tid < 64) {   // in-LDS exclusive scan over tiles (per channel)
                float acc = 0.f;
                #pragma unroll 4
                for (int tt2 = 0; tt2 < NT; tt2++) {
                    float v = s.offs[tt2*64 + tid];
                    s.offs[tt2*64 + tid] = acc;
                    acc += v;
                }
                s.offs[NT*64 + tid] = acc;
            }
            __syncthreads();
            const int kt = kk >> 6;
            const float* pl = ws + OFF_PLOC + ((size_t)b*N + kk)*64;
            const float inv_n = 1.0f / (float)N;
            #pragma unroll
            for (int q = 0; q < 8; q++) {
                int i = wv*8 + q;
                float plg = (kk < N) ? pl[i]      : 0.f;
                float plc = (kk < N) ? pl[i + 32] : 0.f;
                s.y[p*33 + i] = inv_n * (an * (s.offs[kt*64 + i] + plg)
                                            + (s.offs[kt*64 + i + 32] + plc));
            }
            __syncthreads();
            float yv[CI];
            #pragma unroll
            for (int i = 0; i < CI; i++) yv[i] = s.y[p*33 + i];   // conflict-free
            float* part = ws + OFF_PART + (size_t)t*128;
            const int lane = tid & 63;
            #pragma unroll
            for (int q = 0; q < 16; q++) {
                int c = wv*16 + q;                                 // wave-uniform
                float w = s.Wbl[c];
                #pragma unroll
                for (int i4 = 0; i4 < CI; i4 += 4) {
                    float4 w4 = *(const float4*)(s.Wl + c*CI + i4);   // b128 bcast
                    w += w4.x*yv[i4] + w4.y*yv[i4+1] + w4.z*yv[i4+2] + w4.w*yv[i4+3];
                }
                wyv[q] = w;
                float ssum = w, ssq = w*w;
                #pragma unroll
                for (int off = 32; off >= 1; off >>= 1) {
                    ssum += __shfl_xor(ssum, off, 64);
                    ssq  += __shfl_xor(ssq,  off, 64);
                }
                if (lane == 0) { part[c] = ssum; part[64 + c] = ssq; }
            }
            __syncthreads();
        };
        doP4(t0, k0r, a0r, wy0);
        if (has1) doP4(t1, k1r, a1r, wy1);
    }
    gbar(bar, 4*grid);

    //================ P5'+P6: every block reduces partials, then BN+residual ===
    {
        SMemP56& s = sm.p56;
        {   // redundant per-block reduce (L2-resident, coalesced)
            const float* part = ws + OFF_PART;
            const int ch = tid & 127, half = tid >> 7;
            double acc = 0.0;
            #pragma unroll 8
            for (int k2 = 0; k2 < NTILES/2; k2++)
                acc += (double)part[(size_t)(half*(NTILES/2) + k2)*128 + ch];
            s.red[tid] = acc;
        }
        __syncthreads();
        if (tid < 64) {
            double ssum = s.red[tid]      + s.red[tid + 128];
            double ssq  = s.red[tid + 64] + s.red[tid + 192];
            double mean = ssum / (double)NTOT;
            double var  = ssq / (double)NTOT - mean*mean;
            float rs  = (float)(1.0 / sqrt(var + BN_EPS));
            float scl = bn_g[tid] * rs;
            s.ss[tid]      = scl;
            s.ss[64 + tid] = bn_b[tid] - (float)mean * scl;
        }
        __syncthreads();
        auto doP6 = [&](int t, float (&wyv)[16]) {
            const int b = t / NT, n = (t % NT)*64 + p;
            const float* xb = x   + (size_t)b*C*N + n;
            float*       ob = out + (size_t)b*C*N + n;
            #pragma unroll
            for (int q = 0; q < 16; q++) {
                int c = wv*16 + q;                                 // wave-uniform
                ob[(size_t)c*N] = wyv[q]*s.ss[c] + s.ss[64 + c] + xb[(size_t)c*N];
            }
        };
        doP6(t0, wy0);
        if (has1) doP6(t1, wy1);
    }
}

// ------------------------------------------------------------------
extern "C" void kernel_launch(void* const* d_in, const int* in_sizes, int n_in,
                              void* d_out, int out_size, void* d_ws, size_t ws_size,
                              hipStream_t stream)
{
    const float* x     = (const float*)d_in[0];
    const float* g_w   = (const float*)d_in[1];
    const float* g_b   = (const float*)d_in[2];
    const float* th_w  = (const float*)d_in[3];
    const float* th_b  = (const float*)d_in[4];
    const float* ph_w  = (const float*)d_in[5];
    const float* ph_b  = (const float*)d_in[6];
    const float* cp_wt = (const float*)d_in[7];
    const float* cp_wp = (const float*)d_in[8];
    const float* W_w   = (const float*)d_in[9];
    const float* W_b   = (const float*)d_in[10];
    const float* bn_g  = (const float*)d_in[11];
    const float* bn_b  = (const float*)d_in[12];
    float* ws  = (float*)d_ws;
    float* out = (float*)d_out;

    // grid sized so ALL blocks are co-resident (spin barrier cannot deadlock).
    int maxb = 1;
    hipOccupancyMaxActiveBlocksPerMultiprocessor(&maxb, k_mega, 256, 0);
    if (maxb < 1) maxb = 1;
    long long cap = (long long)maxb * 256;
    int grid = (cap < NTILES) ? (int)cap : NTILES;

    hipMemsetAsync((void*)(ws + OFF_BAR), 0, 8*16*sizeof(int), stream);  // reset cells
    hipLaunchKernelGGL(k_mega, dim3(grid), dim3(256), 0, stream,
                       x, g_w, g_b, th_w, th_b, ph_w, ph_b, cp_wt, cp_wp,
                       W_w, W_b, bn_g, bn_b, ws, out);
}

// Round 13
// 78.038 us; speedup vs baseline: 1.8905x; 1.8905x over previous
//
#include <hip/hip_runtime.h>
#include <math.h>

#define B 8
#define C 64
#define CI 32
#define N 2304        // 48*48
#define NT 36         // tiles of 64
#define NTILES (B*NT) // 288
#define NTOT (B*N)    // 18432
#define BN_EPS 1e-5

// ---- workspace layout (float offsets) ----
#define OFF_GX   0                      // [B][N][CI] g_x
#define OFF_A    (OFF_GX + B*N*CI)      // [B][N]
#define OFF_SC   (OFF_A + B*N)          // [B][N] sorted desc
#define OFF_SIDX (OFF_SC + B*N)         // [B][N] int
#define OFF_KN   (OFF_SIDX + B*N)       // [B][N] int: k(n)=#{j: c_j > -a_n}
#define OFF_PLOC (OFF_KN + B*N)         // [B][N][64] excl. in-tile prefix (g | c*g)
#define OFF_TOT  (OFF_PLOC + B*N*64)    // [B][NT][64] tile totals
#define OFF_PART (OFF_TOT + NTILES*64)  // [NTILES][128] f32 per-tile partials
#define OFF_WY   (OFF_PART + NTILES*128) // [B][C][N] wy (pre-BN)

// ------------------------------------------------------------------
// K1: fused projections + bucket-rank. Block = (b, 64-pos tile).
// - g_x for own tile; a for own tile; c for the WHOLE batch (redundant,
//   cheap) -> u64 keys -> 2048-bucket counting scatter in LDS ->
//   rank + k-count by tiny in-bucket scans. Writes GX, A, SC, SIDX, KN.
__global__ __launch_bounds__(256) void k_projrank(
    const float* __restrict__ x,
    const float* __restrict__ g_w, const float* __restrict__ g_b,
    const float* __restrict__ th_w, const float* __restrict__ th_b,
    const float* __restrict__ ph_w, const float* __restrict__ ph_b,
    const float* __restrict__ cp_wt, const float* __restrict__ cp_wp,
    float* __restrict__ ws)
{
    __shared__ unsigned long long su64[N];     // 18432 B bucket-scattered keys
    __shared__ float gw[CI*C];                 // 8192 B [i][c]
    __shared__ float tw[C], pw[C];
    __shared__ float gb[CI];
    __shared__ float tpb[2];
    __shared__ float av[64];                   // own-tile a
    __shared__ unsigned int mkey[64];          // own-tile keys
    __shared__ unsigned int hist[2048];        // 8192 B
    __shared__ unsigned int cursor[2048];      // 8192 B
    __shared__ unsigned int offs[2049];        // 8196 B
    __shared__ int partial[256];
    __shared__ int wavetot[4];

    const int tid = threadIdx.x;
    const int blk = blockIdx.x;                // b*NT + tile
    const int b = blk / NT;
    const int n0 = (blk % NT) * 64;
    const int tile6 = n0 >> 6;
    const int p = tid & 63, wv = tid >> 6;

    //---- A: stage weights, fold cp into tw/pw, zero hist ----
    for (int i = tid; i < CI*C; i += 256) gw[i] = g_w[i];
    if (tid < C) {
        float s = 0.f;
        for (int i = 0; i < CI; i++) s += cp_wt[i] * th_w[i*C + tid];
        tw[tid] = s;
    } else if (tid < 2*C) {
        int c = tid - C; float s = 0.f;
        for (int i = 0; i < CI; i++) s += cp_wp[i] * ph_w[i*C + c];
        pw[c] = s;
    } else if (tid < 2*C + CI) {
        gb[tid - 2*C] = g_b[tid - 2*C];
    } else if (tid == 2*C + CI) {
        float s = 0.f; for (int i = 0; i < CI; i++) s += cp_wt[i]*th_b[i]; tpb[0] = s;
    } else if (tid == 2*C + CI + 1) {
        float s = 0.f; for (int i = 0; i < CI; i++) s += cp_wp[i]*ph_b[i]; tpb[1] = s;
    }
    #pragma unroll
    for (int i = tid; i < 2048; i += 256) hist[i] = 0u;
    __syncthreads();

    //---- B: full-batch c (+a) -> keys in regs + histogram ----
    unsigned int k32r[9];
    #pragma unroll
    for (int r = 0; r < 9; r++) {
        const int j = tid + (r << 8);          // 9*256 = 2304 = N
        const float* xj = x + (size_t)b*C*N + j;
        float aa = 0.f, cc = 0.f;
        #pragma unroll 4
        for (int c4 = 0; c4 < C; c4 += 4) {
            float xv0 = xj[(size_t)(c4+0)*N];  // coalesced over tid
            float xv1 = xj[(size_t)(c4+1)*N];
            float xv2 = xj[(size_t)(c4+2)*N];
            float xv3 = xj[(size_t)(c4+3)*N];
            float4 t4 = *(const float4*)(tw + c4);
            float4 p4 = *(const float4*)(pw + c4);
            aa += t4.x*xv0 + t4.y*xv1 + t4.z*xv2 + t4.w*xv3;
            cc += p4.x*xv0 + p4.y*xv1 + p4.z*xv2 + p4.w*xv3;
        }
        aa += tpb[0]; cc += tpb[1];
        unsigned int u = __float_as_uint(cc);
        unsigned int k32 = (u & 0x80000000u) ? ~u : (u | 0x80000000u);
        k32r[r] = k32;
        atomicAdd(&hist[2047 - (k32 >> 21)], 1u);
        if ((j >> 6) == tile6) {               // own tile (wave-uniform per r)
            av[j & 63] = aa;
            mkey[j & 63] = k32;
            ws[OFF_A + (size_t)b*N + j] = aa;
        }
    }
    __syncthreads();

    //---- D: exclusive scan of 2048-bucket histogram ----
    {
        const int base8 = tid * 8;
        int loc[8]; int ssum = 0;
        #pragma unroll
        for (int k = 0; k < 8; k++) { loc[k] = ssum; ssum += (int)hist[base8 + k]; }
        partial[tid] = ssum;
        __syncthreads();
        int v = partial[tid];
        #pragma unroll
        for (int off = 1; off < 64; off <<= 1) {
            int u = __shfl_up(v, off, 64);
            if ((tid & 63) >= off) v += u;
        }
        if ((tid & 63) == 63) wavetot[tid >> 6] = v;
        __syncthreads();
        int wbase = 0;
        for (int w = 0; w < (tid >> 6); w++) wbase += wavetot[w];
        const int excl = wbase + v - partial[tid];
        #pragma unroll
        for (int k = 0; k < 8; k++) {
            unsigned o = (unsigned)(excl + loc[k]);
            offs[base8 + k] = o;
            cursor[base8 + k] = o;
        }
        if (tid == 0) offs[2048] = N;
        __syncthreads();
    }

    //---- E: counting scatter of u64 keys into bucket segments ----
    #pragma unroll
    for (int r = 0; r < 9; r++) {
        const int j = tid + (r << 8);
        const unsigned int k32 = k32r[r];
        const unsigned pos = atomicAdd(&cursor[2047 - (k32 >> 21)], 1u);
        su64[pos] = ((unsigned long long)k32 << 12) | (unsigned long long)(4095 - j);
    }
    __syncthreads();

    //---- H: g_x for own tile (thread (p, wv): position, channel-octet) ----
    {
        const int n = n0 + p;
        const int ch0 = wv*8;
        const float* xb = x + (size_t)b*C*N + n;
        float accg[8];
        #pragma unroll
        for (int j = 0; j < 8; j++) accg[j] = 0.f;
        #pragma unroll 4
        for (int c4 = 0; c4 < C; c4 += 4) {
            float xv0 = xb[(size_t)(c4+0)*N];  // coalesced over p
            float xv1 = xb[(size_t)(c4+1)*N];
            float xv2 = xb[(size_t)(c4+2)*N];
            float xv3 = xb[(size_t)(c4+3)*N];
            #pragma unroll
            for (int j = 0; j < 8; j++) {
                float4 g4 = *(const float4*)(gw + (ch0+j)*C + c4);   // b128 bcast
                accg[j] += g4.x*xv0 + g4.y*xv1 + g4.z*xv2 + g4.w*xv3;
            }
        }
        #pragma unroll
        for (int j = 0; j < 8; j++) accg[j] += gb[ch0 + j];
        float* gxp = ws + OFF_GX + ((size_t)(b*N + n))*CI + ch0;
        *(float4*)(gxp)     = make_float4(accg[0], accg[1], accg[2], accg[3]);
        *(float4*)(gxp + 4) = make_float4(accg[4], accg[5], accg[6], accg[7]);
    }

    //---- F: ranks of own 64 elements -> SC/SIDX; G: k-count -> KN ----
    if (tid < 64) {
        const int m = n0 + tid;
        const unsigned int k32m = mkey[tid];
        const unsigned long long my =
            ((unsigned long long)k32m << 12) | (unsigned long long)(4095 - m);
        const int bt = 2047 - (int)(k32m >> 21);
        const int lo = (int)offs[bt], hi = (int)offs[bt + 1];
        int r = lo;                            // all earlier buckets have key > my
        for (int e = lo; e < hi; e++) r += (su64[e] > my) ? 1 : 0;
        unsigned int u = (k32m & 0x80000000u) ? (k32m & 0x7fffffffu) : ~k32m;
        ws[OFF_SC + (size_t)b*N + r] = __uint_as_float(u);
        ((int*)(ws + OFF_SIDX))[(size_t)b*N + r] = m;
    } else if (tid < 128) {
        const int p2 = tid - 64;
        const int n = n0 + p2;
        unsigned int ua  = __float_as_uint(-av[p2]);
        unsigned int t32 = (ua & 0x80000000u) ? ~ua : (ua | 0x80000000u);
        const unsigned long long thr = ((unsigned long long)t32 << 12) | 4095ull;
        const int bt = 2047 - (int)(t32 >> 21);
        const int lo = (int)offs[bt], hi = (int)offs[bt + 1];
        int k = lo;
        for (int e = lo; e < hi; e++) k += (su64[e] > thr) ? 1 : 0;
        ((int*)(ws + OFF_KN))[(size_t)b*N + n] = k;
    }
}

// ------------------------------------------------------------------
// K2: 256 thr, two-level scan. Wave w: 16-step local prefix of
// [g[m,i] ; c_m*g[m,i]] (64 channels); segment offsets recombine.
__global__ __launch_bounds__(256) void k_prefix(float* __restrict__ ws)
{
    __shared__ int   sidx[64];
    __shared__ float scv[64];
    __shared__ float pl_lds[64*64];      // [k][ch] (16 KB)
    __shared__ float wtot[4*64];
    __shared__ float segoff[4*64];
    const int tid = threadIdx.x;
    const int blk = blockIdx.x;          // b*NT + t
    const int b = blk / NT, t = blk % NT;
    const int k0 = t * 64;
    if (tid < 64) {
        sidx[tid] = ((const int*)(ws + OFF_SIDX))[b*N + k0 + tid];
        scv[tid]  = ws[OFF_SC + b*N + k0 + tid];
    }
    __syncthreads();
    const int w   = tid >> 6;            // k-segment
    const int ch  = tid & 63;
    const int chm = ch & 31;
    const bool isCG = ch >= 32;
    const float* gx = ws + OFF_GX + (size_t)b*N*CI;
    float acc = 0.f;
    #pragma unroll
    for (int kk = 0; kk < 16; kk++) {
        int k = w*16 + kk;
        int m = sidx[k];                               // wave-uniform
        float gval = gx[(size_t)m*CI + chm];           // 128B gather, 2-way bcast
        float v = isCG ? gval * scv[k] : gval;
        pl_lds[k*64 + ch] = acc;
        acc += v;
    }
    wtot[w*64 + ch] = acc;
    __syncthreads();
    if (tid < 64) {
        float s = 0.f;
        #pragma unroll
        for (int ww = 0; ww < 4; ww++) { segoff[ww*64 + tid] = s; s += wtot[ww*64 + tid]; }
        ws[OFF_TOT + ((size_t)b*NT + t)*64 + tid] = s;     // tile total
    }
    __syncthreads();
    float* pl = ws + OFF_PLOC + ((size_t)b*N + k0)*64;
    #pragma unroll
    for (int r4 = 0; r4 < 16; r4++) {
        int r = (tid >> 6) + r4*4;
        pl[(size_t)r*64 + ch] = pl_lds[r*64 + ch] + segoff[(r >> 4)*64 + ch];
    }
}

// ------------------------------------------------------------------
// K3: per (b,tile): y via KN lookup + prefix; wy = W·y + W_b stored to
// OFF_WY; per-block BN partials (f32, no atomics).
__global__ __launch_bounds__(256) void k_stats(
    const float* __restrict__ W_w, const float* __restrict__ W_b,
    float* __restrict__ ws)
{
    __shared__ float offs_lds[(NT+1)*64];    // 9472 B
    __shared__ float y_lds[64*33];           // 8448 B
    __shared__ float Wl[C*CI];               // 8192 B
    __shared__ float Wbl[C];
    const int tid = threadIdx.x;
    const int blk = blockIdx.x;
    const int b = blk / NT, tile = blk % NT;

    for (int i = tid; i < C*CI; i += 256) Wl[i] = W_w[i];
    if (tid < C) Wbl[tid] = W_b[tid];
    {   // stage tile totals (coalesced)
        const float* tot = ws + OFF_TOT + (size_t)b*NT*64;
        for (int i = tid; i < NT*64; i += 256) offs_lds[i] = tot[i];
    }
    __syncthreads();
    if (tid < 64) {   // in-LDS exclusive scan over tiles (per channel)
        float acc = 0.f;
        #pragma unroll 4
        for (int t = 0; t < NT; t++) {
            float v = offs_lds[t*64 + tid];
            offs_lds[t*64 + tid] = acc;
            acc += v;
        }
        offs_lds[NT*64 + tid] = acc;
    }
    __syncthreads();

    const int p = tid & 63, wv = tid >> 6;
    const int n = tile*64 + p;
    const float an = ws[OFF_A + b*N + n];
    const int k = ((const int*)(ws + OFF_KN))[b*N + n];
    const int kt = k >> 6;
    const float* pl = ws + OFF_PLOC + ((size_t)b*N + k)*64;
    const float inv_n = 1.0f / (float)N;
    #pragma unroll
    for (int q = 0; q < 8; q++) {
        int i = wv*8 + q;
        float plg = (k < N) ? pl[i]      : 0.f;
        float plc = (k < N) ? pl[i + 32] : 0.f;
        float Pg = offs_lds[kt*64 + i]      + plg;
        float Pc = offs_lds[kt*64 + i + 32] + plc;
        y_lds[p*33 + i] = inv_n * (an * Pg + Pc);
    }
    __syncthreads();

    // hoist y[p][0..31] to registers (stride-33 -> conflict-free)
    float yv[CI];
    #pragma unroll
    for (int i = 0; i < CI; i++) yv[i] = y_lds[p*33 + i];

    const int lane = tid & 63;
    float* part = ws + OFF_PART + (size_t)blk*128;
    float* wyb  = ws + OFF_WY + (size_t)b*C*N + n;
    #pragma unroll
    for (int q = 0; q < 16; q++) {
        int c = wv*16 + q;                             // wave-uniform
        float wyv = Wbl[c];
        #pragma unroll
        for (int i4 = 0; i4 < CI; i4 += 4) {
            float4 w4 = *(const float4*)(Wl + c*CI + i4);   // b128 broadcast
            wyv += w4.x*yv[i4] + w4.y*yv[i4+1] + w4.z*yv[i4+2] + w4.w*yv[i4+3];
        }
        wyb[(size_t)c*N] = wyv;                        // coalesced over lanes
        float s = wyv, sq = wyv * wyv;
        #pragma unroll
        for (int off = 32; off >= 1; off >>= 1) {
            s  += __shfl_xor(s,  off, 64);
            sq += __shfl_xor(sq, off, 64);
        }
        if (lane == 0) { part[c] = s; part[64 + c] = sq; }
    }
}

// ------------------------------------------------------------------
// K4: per-block redundant reduce of partials -> scale/shift, then stream
// out = wy*scale + shift + x. 288 blocks x 4 float4/thread.
__global__ __launch_bounds__(256) void k_final(
    const float* __restrict__ x,
    const float* __restrict__ bn_g, const float* __restrict__ bn_b,
    const float* __restrict__ ws, float* __restrict__ out)
{
    __shared__ double red[256];
    __shared__ float ssc[128];               // scale[64], shift[64]
    const int tid = threadIdx.x;
    {   // redundant per-block reduce (L2-resident, coalesced)
        const float* part = ws + OFF_PART;
        const int ch = tid & 127, half = tid >> 7;
        double acc = 0.0;
        #pragma unroll 8
        for (int k2 = 0; k2 < NTILES/2; k2++)
            acc += (double)part[(size_t)(half*(NTILES/2) + k2)*128 + ch];
        red[tid] = acc;
    }
    __syncthreads();
    if (tid < 64) {
        double ssum = red[tid]      + red[tid + 128];
        double ssq  = red[tid + 64] + red[tid + 192];
        double mean = ssum / (double)NTOT;
        double var  = ssq / (double)NTOT - mean*mean;
        float rs  = (float)(1.0 / sqrt(var + BN_EPS));
        float scl = bn_g[tid] * rs;
        ssc[tid]      = scl;
        ssc[64 + tid] = bn_b[tid] - (float)mean * scl;
    }
    __syncthreads();
    const float4* wy4 = (const float4*)(ws + OFF_WY);
    const float4* x4p = (const float4*)x;
    float4*       o4p = (float4*)out;
    #pragma unroll
    for (int j = 0; j < 4; j++) {
        const int idx = blockIdx.x*1024 + j*256 + tid;     // float4 index
        const float4 w4 = wy4[idx];
        const float4 xv = x4p[idx];
        const int c = ((idx*4) / N) & 63;                  // row-uniform (N%4==0)
        const float s = ssc[c], sh = ssc[64 + c];
        float4 o;
        o.x = w4.x*s + sh + xv.x;
        o.y = w4.y*s + sh + xv.y;
        o.z = w4.z*s + sh + xv.z;
        o.w = w4.w*s + sh + xv.w;
        o4p[idx] = o;
    }
}

// ------------------------------------------------------------------
extern "C" void kernel_launch(void* const* d_in, const int* in_sizes, int n_in,
                              void* d_out, int out_size, void* d_ws, size_t ws_size,
                              hipStream_t stream)
{
    const float* x     = (const float*)d_in[0];
    const float* g_w   = (const float*)d_in[1];
    const float* g_b   = (const float*)d_in[2];
    const float* th_w  = (const float*)d_in[3];
    const float* th_b  = (const float*)d_in[4];
    const float* ph_w  = (const float*)d_in[5];
    const float* ph_b  = (const float*)d_in[6];
    const float* cp_wt = (const float*)d_in[7];
    const float* cp_wp = (const float*)d_in[8];
    const float* W_w   = (const float*)d_in[9];
    const float* W_b   = (const float*)d_in[10];
    const float* bn_g  = (const float*)d_in[11];
    const float* bn_b  = (const float*)d_in[12];
    float* ws  = (float*)d_ws;
    float* out = (float*)d_out;

    hipLaunchKernelGGL(k_projrank, dim3(NTILES), dim3(256), 0, stream,
                       x, g_w, g_b, th_w, th_b, ph_w, ph_b, cp_wt, cp_wp, ws);
    hipLaunchKernelGGL(k_prefix,   dim3(NTILES), dim3(256), 0, stream, ws);
    hipLaunchKernelGGL(k_stats,    dim3(NTILES), dim3(256), 0, stream, W_w, W_b, ws);
    hipLaunchKernelGGL(k_final,    dim3(NTILES), dim3(256), 0, stream,
                       x, bn_g, bn_b, ws, out);
}

// Round 17
// 71.764 us; speedup vs baseline: 2.0558x; 1.0874x over previous
//
#include <hip/hip_runtime.h>
#include <math.h>

#define B 8
#define C 64
#define CI 32
#define N 2304        // 48*48
#define NT 36         // tiles of 64
#define NTILES (B*NT) // 288
#define NTOT (B*N)    // 18432
#define BN_EPS 1e-5

// ---- workspace layout (float offsets) ----
#define OFF_GX   0                      // [B][N][CI] g_x
#define OFF_A    (OFF_GX + B*N*CI)      // [B][N]
#define OFF_C    (OFF_A + B*N)          // [B][N]
#define OFF_SC   (OFF_C + B*N)          // [B][N] sorted desc
#define OFF_SIDX (OFF_SC + B*N)         // [B][N] int
#define OFF_KN   (OFF_SIDX + B*N)       // [B][N] int: k(n)=#{j: c_j > -a_n}
#define OFF_PLOC (OFF_KN + B*N)         // [B][N][64] excl. in-tile prefix (g | c*g)
#define OFF_TOT  (OFF_PLOC + B*N*64)    // [B][NT][64] tile totals
#define OFF_PART (OFF_TOT + B*NT*64)    // [NTILES][128] f32 per-tile partials
#define OFF_WY   (OFF_PART + NTILES*128) // [B][C][N] wy (pre-BN)

// ------------------------------------------------------------------
// K1: 288 blocks x 256 thr. Thread (p, wv): position, channel-octet.
// Weights g_w/g_b read DIRECTLY from global with wave-uniform addresses
// (scalar-path / broadcast; L1-resident 8KB) -- no LDS staging, LDS pipe free.
__global__ __launch_bounds__(256) void k_proj(
    const float* __restrict__ x,
    const float* __restrict__ g_w, const float* __restrict__ g_b,
    const float* __restrict__ th_w, const float* __restrict__ th_b,
    const float* __restrict__ ph_w, const float* __restrict__ ph_b,
    const float* __restrict__ cp_wt, const float* __restrict__ cp_wp,
    float* __restrict__ ws)
{
    __shared__ float tw[C], pw[C];
    __shared__ float tpb[2];
    const int tid = threadIdx.x;
    const int blk = blockIdx.x;     // b*NT + t
    const int b  = blk / NT;
    const int n0 = (blk % NT) * 64;

    if (tid < C) {
        float s = 0.f;
        for (int i = 0; i < CI; i++) s += cp_wt[i] * th_w[i*C + tid];
        tw[tid] = s;
    } else if (tid < 2*C) {
        int c = tid - C; float s = 0.f;
        for (int i = 0; i < CI; i++) s += cp_wp[i] * ph_w[i*C + c];
        pw[c] = s;
    } else if (tid == 2*C) {
        float s = 0.f; for (int i = 0; i < CI; i++) s += cp_wt[i]*th_b[i]; tpb[0] = s;
    } else if (tid == 2*C + 1) {
        float s = 0.f; for (int i = 0; i < CI; i++) s += cp_wp[i]*ph_b[i]; tpb[1] = s;
    }
    __syncthreads();

    const int p = tid & 63, wv = tid >> 6;   // wv is wave-uniform (tid>>6)
    const int n = n0 + p;
    const int ch0 = wv*8;
    const float* xb = x + (size_t)b*C*N + n;
    float accg[8];
    #pragma unroll
    for (int j = 0; j < 8; j++) accg[j] = 0.f;
    float aa = 0.f, cc = 0.f;
    #pragma unroll 4
    for (int c4 = 0; c4 < C; c4 += 4) {
        float xv0 = xb[(size_t)(c4+0)*N];          // coalesced over p
        float xv1 = xb[(size_t)(c4+1)*N];
        float xv2 = xb[(size_t)(c4+2)*N];
        float xv3 = xb[(size_t)(c4+3)*N];
        if (wv == 0) {                              // wave-uniform branch
            float4 t4 = *(const float4*)(tw + c4);
            aa += t4.x*xv0 + t4.y*xv1 + t4.z*xv2 + t4.w*xv3;
        } else if (wv == 1) {
            float4 p4 = *(const float4*)(pw + c4);
            cc += p4.x*xv0 + p4.y*xv1 + p4.z*xv2 + p4.w*xv3;
        }
        #pragma unroll
        for (int j = 0; j < 8; j++) {
            // uniform global read (ch0, c4 wave-uniform) -> scalar/broadcast path
            float4 g4 = *(const float4*)(g_w + (ch0+j)*C + c4);
            accg[j] += g4.x*xv0 + g4.y*xv1 + g4.z*xv2 + g4.w*xv3;
        }
    }
    #pragma unroll
    for (int j = 0; j < 8; j++) accg[j] += g_b[ch0 + j];   // uniform global
    float* gxp = ws + OFF_GX + ((size_t)(b*N + n))*CI + ch0;
    *(float4*)(gxp)     = make_float4(accg[0], accg[1], accg[2], accg[3]);
    *(float4*)(gxp + 4) = make_float4(accg[4], accg[5], accg[6], accg[7]);
    if (wv == 0) ws[OFF_A + b*N + n] = aa + tpb[0];
    else if (wv == 1) ws[OFF_C + b*N + n] = cc + tpb[1];
}

// ------------------------------------------------------------------
// K2: rank-by-counting with u64 keys + k-count.
// key = ord(c)<<12 | (4095-j): key_j > key_m <=> (c_j>c_m)||(c_j==c_m && j<m)
// thr = ord(-a_n)<<12 | 4095:  key_j > thr   <=> c_j > -a_n  (ties at
// a_n+c_m==0 contribute (a_n+c_m)*g = 0 downstream, so boundary is exact)
__global__ __launch_bounds__(256) void k_rank(float* __restrict__ ws)
{
    __shared__ __align__(16) unsigned long long keys[N];   // 18 KB
    __shared__ int partial[256];
    __shared__ int partial2[256];
    __shared__ float av[64];
    const int tid = threadIdx.x;
    const int blk = blockIdx.x;      // b*NT + mtile
    const int b  = blk / NT;
    const int m0 = (blk % NT) * 64;
    const float* cb = ws + OFF_C + (size_t)b*N;
    for (int i = tid; i < N; i += 256) {
        unsigned int u = __float_as_uint(cb[i]);
        unsigned int k32 = (u & 0x80000000u) ? ~u : (u | 0x80000000u);
        keys[i] = ((unsigned long long)k32 << 12) | (unsigned long long)(4095 - i);
    }
    if (tid < 64) av[tid] = ws[OFF_A + b*N + m0 + tid];
    __syncthreads();
    const int p = tid & 63;
    const int wv = tid >> 6;                   // wave id = j-quarter
    const unsigned long long my = keys[m0 + p];
    unsigned int ua  = __float_as_uint(-av[p]);
    unsigned int t32 = (ua & 0x80000000u) ? ~ua : (ua | 0x80000000u);
    const unsigned long long thr = ((unsigned long long)t32 << 12) | 4095ull;
    const ulonglong2* kp = (const ulonglong2*)keys;
    int c0=0,c1=0,c2=0,c3=0, d0=0,d1=0,d2=0,d3=0;
    const int base = wv * (N/8);
    #pragma unroll 4
    for (int t2 = 0; t2 < N/8; t2 += 2) {      // 2 x ulonglong2 per iter
        ulonglong2 ka = kp[base + t2];
        ulonglong2 kb = kp[base + t2 + 1];
        c0 += (ka.x > my);  c1 += (ka.y > my);
        c2 += (kb.x > my);  c3 += (kb.y > my);
        d0 += (ka.x > thr); d1 += (ka.y > thr);
        d2 += (kb.x > thr); d3 += (kb.y > thr);
    }
    partial[tid]  = (c0 + c1) + (c2 + c3);
    partial2[tid] = (d0 + d1) + (d2 + d3);
    __syncthreads();
    if (tid < 64) {
        int rank = partial[tid] + partial[tid+64] + partial[tid+128] + partial[tid+192];
        int kc   = partial2[tid] + partial2[tid+64] + partial2[tid+128] + partial2[tid+192];
        unsigned long long km = keys[m0 + tid];
        unsigned int k32 = (unsigned int)(km >> 12);
        unsigned int u = (k32 & 0x80000000u) ? (k32 & 0x7fffffffu) : ~k32;
        ws[OFF_SC + b*N + rank] = __uint_as_float(u);
        ((int*)(ws + OFF_SIDX))[b*N + rank] = m0 + tid;
        ((int*)(ws + OFF_KN))[b*N + m0 + tid] = kc;
    }
}

// ------------------------------------------------------------------
// K3: 256 thr, two-level scan. Wave w: 16-step local prefix of
// [g[m,i] ; c_m*g[m,i]] (64 channels); segment offsets recombine.
__global__ __launch_bounds__(256) void k_prefix(float* __restrict__ ws)
{
    __shared__ int   sidx[64];
    __shared__ float scv[64];
    __shared__ float pl_lds[64*64];      // [k][ch] (16 KB)
    __shared__ float wtot[4*64];
    __shared__ float segoff[4*64];
    const int tid = threadIdx.x;
    const int blk = blockIdx.x;          // b*NT + t
    const int b = blk / NT, t = blk % NT;
    const int k0 = t * 64;
    if (tid < 64) {
        sidx[tid] = ((const int*)(ws + OFF_SIDX))[b*N + k0 + tid];
        scv[tid]  = ws[OFF_SC + b*N + k0 + tid];
    }
    __syncthreads();
    const int w   = tid >> 6;            // k-segment
    const int ch  = tid & 63;
    const int chm = ch & 31;
    const bool isCG = ch >= 32;
    const float* gx = ws + OFF_GX + (size_t)b*N*CI;
    float acc = 0.f;
    #pragma unroll
    for (int kk = 0; kk < 16; kk++) {
        int k = w*16 + kk;
        int m = sidx[k];                               // wave-uniform
        float gval = gx[(size_t)m*CI + chm];           // 128B gather, 2-way bcast
        float v = isCG ? gval * scv[k] : gval;
        pl_lds[k*64 + ch] = acc;
        acc += v;
    }
    wtot[w*64 + ch] = acc;
    __syncthreads();
    if (tid < 64) {
        float s = 0.f;
        #pragma unroll
        for (int ww = 0; ww < 4; ww++) { segoff[ww*64 + tid] = s; s += wtot[ww*64 + tid]; }
        ws[OFF_TOT + ((size_t)b*NT + t)*64 + tid] = s;     // tile total
    }
    __syncthreads();
    float* pl = ws + OFF_PLOC + ((size_t)b*N + k0)*64;
    #pragma unroll
    for (int r4 = 0; r4 < 16; r4++) {
        int r = (tid >> 6) + r4*4;
        pl[(size_t)r*64 + ch] = pl_lds[r*64 + ch] + segoff[(r >> 4)*64 + ch];
    }
}

// ------------------------------------------------------------------
// K4: per (b,tile): y via KN lookup + prefix; wy = W·y + W_b stored to
// OFF_WY; per-block BN partials (f32, no atomics). W_w/W_b read directly
// from global with wave-uniform addresses (no LDS staging).
__global__ __launch_bounds__(256) void k_stats(
    const float* __restrict__ W_w, const float* __restrict__ W_b,
    float* __restrict__ ws)
{
    __shared__ float offs_lds[(NT+1)*64];    // 9472 B
    __shared__ float y_lds[64*33];           // 8448 B
    const int tid = threadIdx.x;
    const int blk = blockIdx.x;
    const int b = blk / NT, tile = blk % NT;

    {   // stage tile totals (coalesced)
        const float* tot = ws + OFF_TOT + (size_t)b*NT*64;
        for (int i = tid; i < NT*64; i += 256) offs_lds[i] = tot[i];
    }
    __syncthreads();
    if (tid < 64) {   // in-LDS exclusive scan over tiles (per channel)
        float acc = 0.f;
        #pragma unroll 4
        for (int t = 0; t < NT; t++) {
            float v = offs_lds[t*64 + tid];
            offs_lds[t*64 + tid] = acc;
            acc += v;
        }
        offs_lds[NT*64 + tid] = acc;
    }
    __syncthreads();

    const int p = tid & 63, wv = tid >> 6;
    const int n = tile*64 + p;
    const float an = ws[OFF_A + b*N + n];
    const int k = ((const int*)(ws + OFF_KN))[b*N + n];
    const int kt = k >> 6;
    const float* pl = ws + OFF_PLOC + ((size_t)b*N + k)*64;
    const float inv_n = 1.0f / (float)N;
    #pragma unroll
    for (int q = 0; q < 8; q++) {
        int i = wv*8 + q;
        float plg = (k < N) ? pl[i]      : 0.f;
        float plc = (k < N) ? pl[i + 32] : 0.f;
        float Pg = offs_lds[kt*64 + i]      + plg;
        float Pc = offs_lds[kt*64 + i + 32] + plc;
        y_lds[p*33 + i] = inv_n * (an * Pg + Pc);
    }
    __syncthreads();

    // hoist y[p][0..31] to registers (stride-33 -> conflict-free)
    float yv[CI];
    #pragma unroll
    for (int i = 0; i < CI; i++) yv[i] = y_lds[p*33 + i];

    const int lane = tid & 63;
    float* part = ws + OFF_PART + (size_t)blk*128;
    float* wyb  = ws + OFF_WY + (size_t)b*C*N + n;
    #pragma unroll
    for (int q = 0; q < 16; q++) {
        int c = wv*16 + q;                             // wave-uniform
        float wyv = W_b[c];                            // uniform global
        #pragma unroll
        for (int i4 = 0; i4 < CI; i4 += 4) {
            // uniform global read -> scalar/broadcast path (L1-resident 8KB)
            float4 w4 = *(const float4*)(W_w + c*CI + i4);
            wyv += w4.x*yv[i4] + w4.y*yv[i4+1] + w4.z*yv[i4+2] + w4.w*yv[i4+3];
        }
        wyb[(size_t)c*N] = wyv;                        // coalesced over lanes
        float s = wyv, sq = wyv * wyv;
        #pragma unroll
        for (int off = 32; off >= 1; off >>= 1) {
            s  += __shfl_xor(s,  off, 64);
            sq += __shfl_xor(sq, off, 64);
        }
        if (lane == 0) { part[c] = s; part[64 + c] = sq; }
    }
}

// ------------------------------------------------------------------
// K5: per-block redundant reduce of partials -> scale/shift, then stream
// out = wy*scale + shift + x. 288 blocks x 4 float4/thread.
__global__ __launch_bounds__(256) void k_final(
    const float* __restrict__ x,
    const float* __restrict__ bn_g, const float* __restrict__ bn_b,
    const float* __restrict__ ws, float* __restrict__ out)
{
    __shared__ double red[256];
    __shared__ float ssc[128];               // scale[64], shift[64]
    const int tid = threadIdx.x;
    {   // redundant per-block reduce (L2-resident, coalesced)
        const float* part = ws + OFF_PART;
        const int ch = tid & 127, half = tid >> 7;
        double acc = 0.0;
        #pragma unroll 8
        for (int k2 = 0; k2 < NTILES/2; k2++)
            acc += (double)part[(size_t)(half*(NTILES/2) + k2)*128 + ch];
        red[tid] = acc;
    }
    __syncthreads();
    if (tid < 64) {
        double ssum = red[tid]      + red[tid + 128];
        double ssq  = red[tid + 64] + red[tid + 192];
        double mean = ssum / (double)NTOT;
        double var  = ssq / (double)NTOT - mean*mean;
        float rs  = (float)(1.0 / sqrt(var + BN_EPS));
        float scl = bn_g[tid] * rs;
        ssc[tid]      = scl;
        ssc[64 + tid] = bn_b[tid] - (float)mean * scl;
    }
    __syncthreads();
    const float4* wy4 = (const float4*)(ws + OFF_WY);
    const float4* x4p = (const float4*)x;
    float4*       o4p = (float4*)out;
    #pragma unroll
    for (int j = 0; j < 4; j++) {
        const int idx = blockIdx.x*1024 + j*256 + tid;     // float4 index
        const float4 w4 = wy4[idx];
        const float4 xv = x4p[idx];
        const int c = ((idx*4) / N) & 63;                  // row-uniform (N%4==0)
        const float s = ssc[c], sh = ssc[64 + c];
        float4 o;
        o.x = w4.x*s + sh + xv.x;
        o.y = w4.y*s + sh + xv.y;
        o.z = w4.z*s + sh + xv.z;
        o.w = w4.w*s + sh + xv.w;
        o4p[idx] = o;
    }
}

// ------------------------------------------------------------------
extern "C" void kernel_launch(void* const* d_in, const int* in_sizes, int n_in,
                              void* d_out, int out_size, void* d_ws, size_t ws_size,
                              hipStream_t stream)
{
    const float* x     = (const float*)d_in[0];
    const float* g_w   = (const float*)d_in[1];
    const float* g_b   = (const float*)d_in[2];
    const float* th_w  = (const float*)d_in[3];
    const float* th_b  = (const float*)d_in[4];
    const float* ph_w  = (const float*)d_in[5];
    const float* ph_b  = (const float*)d_in[6];
    const float* cp_wt = (const float*)d_in[7];
    const float* cp_wp = (const float*)d_in[8];
    const float* W_w   = (const float*)d_in[9];
    const float* W_b   = (const float*)d_in[10];
    const float* bn_g  = (const float*)d_in[11];
    const float* bn_b  = (const float*)d_in[12];
    float* ws  = (float*)d_ws;
    float* out = (float*)d_out;

    hipLaunchKernelGGL(k_proj,   dim3(NTILES), dim3(256), 0, stream,
                       x, g_w, g_b, th_w, th_b, ph_w, ph_b, cp_wt, cp_wp, ws);
    hipLaunchKernelGGL(k_rank,   dim3(NTILES), dim3(256), 0, stream, ws);
    hipLaunchKernelGGL(k_prefix, dim3(NTILES), dim3(256), 0, stream, ws);
    hipLaunchKernelGGL(k_stats,  dim3(NTILES), dim3(256), 0, stream, W_w, W_b, ws);
    hipLaunchKernelGGL(k_final,  dim3(NTILES), dim3(256), 0, stream,
                       x, bn_g, bn_b, ws, out);
}

// Round 18
// 64.086 us; speedup vs baseline: 2.3021x; 1.1198x over previous
//
#include <hip/hip_runtime.h>
#include <math.h>

#define B 8
#define C 64
#define CI 32
#define N 2304        // 48*48
#define NT 36         // tiles of 64
#define NTILES (B*NT) // 288
#define NTOT (B*N)    // 18432
#define BN_EPS 1e-5

// ---- workspace layout (float offsets) ----
#define OFF_GX   0                      // [B][N][CI] g_x
#define OFF_A    (OFF_GX + B*N*CI)      // [B][N]
#define OFF_C    (OFF_A + B*N)          // [B][N]
#define OFF_SC   (OFF_C + B*N)          // [B][N] sorted desc
#define OFF_SIDX (OFF_SC + B*N)         // [B][N] int
#define OFF_KN   (OFF_SIDX + B*N)       // [B][N] int: k(n)=#{j: c_j > -a_n}
#define OFF_PLOC (OFF_KN + B*N)         // [B][N][64] excl. in-tile prefix (g | c*g)
#define OFF_TOT  (OFF_PLOC + B*N*64)    // [B][NT][64] tile totals
#define OFF_PART (OFF_TOT + B*NT*64)    // [NTILES][128] f32 per-tile partials
#define OFF_WY   (OFF_PART + NTILES*128) // [B][C][N] wy (pre-BN)

// ------------------------------------------------------------------
// K1: 288 blocks x 256 thr. Thread (p, wv): position, channel-octet.
// gw staged in LDS (one-time, then broadcast reads -- verified faster than
// per-lane same-address global loads, round 17 A/B).
__global__ __launch_bounds__(256) void k_proj(
    const float* __restrict__ x,
    const float* __restrict__ g_w, const float* __restrict__ g_b,
    const float* __restrict__ th_w, const float* __restrict__ th_b,
    const float* __restrict__ ph_w, const float* __restrict__ ph_b,
    const float* __restrict__ cp_wt, const float* __restrict__ cp_wp,
    float* __restrict__ ws)
{
    __shared__ float gw[CI*C];      // [i][c] (c contiguous)
    __shared__ float tw[C], pw[C];
    __shared__ float gb[CI];
    __shared__ float tpb[2];
    const int tid = threadIdx.x;
    const int blk = blockIdx.x;     // b*NT + t
    const int b  = blk / NT;
    const int n0 = (blk % NT) * 64;

    for (int i = tid; i < CI*C; i += 256) gw[i] = g_w[i];
    if (tid < C) {
        float s = 0.f;
        for (int i = 0; i < CI; i++) s += cp_wt[i] * th_w[i*C + tid];
        tw[tid] = s;
    } else if (tid < 2*C) {
        int c = tid - C; float s = 0.f;
        for (int i = 0; i < CI; i++) s += cp_wp[i] * ph_w[i*C + c];
        pw[c] = s;
    } else if (tid < 2*C + CI) {
        gb[tid - 2*C] = g_b[tid - 2*C];
    } else if (tid == 2*C + CI) {
        float s = 0.f; for (int i = 0; i < CI; i++) s += cp_wt[i]*th_b[i]; tpb[0] = s;
    } else if (tid == 2*C + CI + 1) {
        float s = 0.f; for (int i = 0; i < CI; i++) s += cp_wp[i]*ph_b[i]; tpb[1] = s;
    }
    __syncthreads();

    const int p = tid & 63, wv = tid >> 6;
    const int n = n0 + p;
    const int ch0 = wv*8;
    const float* xb = x + (size_t)b*C*N + n;
    float accg[8];
    #pragma unroll
    for (int j = 0; j < 8; j++) accg[j] = 0.f;
    float aa = 0.f, cc = 0.f;
    #pragma unroll 4
    for (int c4 = 0; c4 < C; c4 += 4) {
        float xv0 = xb[(size_t)(c4+0)*N];          // coalesced over p
        float xv1 = xb[(size_t)(c4+1)*N];
        float xv2 = xb[(size_t)(c4+2)*N];
        float xv3 = xb[(size_t)(c4+3)*N];
        if (wv == 0) {                              // wave-uniform branch
            float4 t4 = *(const float4*)(tw + c4);
            aa += t4.x*xv0 + t4.y*xv1 + t4.z*xv2 + t4.w*xv3;
        } else if (wv == 1) {
            float4 p4 = *(const float4*)(pw + c4);
            cc += p4.x*xv0 + p4.y*xv1 + p4.z*xv2 + p4.w*xv3;
        }
        #pragma unroll
        for (int j = 0; j < 8; j++) {
            float4 g4 = *(const float4*)(gw + (ch0+j)*C + c4);   // b128 broadcast
            accg[j] += g4.x*xv0 + g4.y*xv1 + g4.z*xv2 + g4.w*xv3;
        }
    }
    #pragma unroll
    for (int j = 0; j < 8; j++) accg[j] += gb[ch0 + j];
    float* gxp = ws + OFF_GX + ((size_t)(b*N + n))*CI + ch0;
    *(float4*)(gxp)     = make_float4(accg[0], accg[1], accg[2], accg[3]);
    *(float4*)(gxp + 4) = make_float4(accg[4], accg[5], accg[6], accg[7]);
    if (wv == 0) ws[OFF_A + b*N + n] = aa + tpb[0];
    else if (wv == 1) ws[OFF_C + b*N + n] = cc + tpb[1];
}

// ------------------------------------------------------------------
// K2: rank-by-counting with u64 keys + k-count.
// key = ord(c)<<12 | (4095-j): key_j > key_m <=> (c_j>c_m)||(c_j==c_m && j<m)
// thr = ord(-a_n)<<12 | 4095:  key_j > thr   <=> c_j > -a_n  (ties at
// a_n+c_m==0 contribute (a_n+c_m)*g = 0 downstream, so boundary is exact)
__global__ __launch_bounds__(256) void k_rank(float* __restrict__ ws)
{
    __shared__ __align__(16) unsigned long long keys[N];   // 18 KB
    __shared__ int partial[256];
    __shared__ int partial2[256];
    __shared__ float av[64];
    const int tid = threadIdx.x;
    const int blk = blockIdx.x;      // b*NT + mtile
    const int b  = blk / NT;
    const int m0 = (blk % NT) * 64;
    const float* cb = ws + OFF_C + (size_t)b*N;
    for (int i = tid; i < N; i += 256) {
        unsigned int u = __float_as_uint(cb[i]);
        unsigned int k32 = (u & 0x80000000u) ? ~u : (u | 0x80000000u);
        keys[i] = ((unsigned long long)k32 << 12) | (unsigned long long)(4095 - i);
    }
    if (tid < 64) av[tid] = ws[OFF_A + b*N + m0 + tid];
    __syncthreads();
    const int p = tid & 63;
    const int wv = tid >> 6;                   // wave id = j-quarter
    const unsigned long long my = keys[m0 + p];
    unsigned int ua  = __float_as_uint(-av[p]);
    unsigned int t32 = (ua & 0x80000000u) ? ~ua : (ua | 0x80000000u);
    const unsigned long long thr = ((unsigned long long)t32 << 12) | 4095ull;
    const ulonglong2* kp = (const ulonglong2*)keys;
    int c0=0,c1=0,c2=0,c3=0, d0=0,d1=0,d2=0,d3=0;
    const int base = wv * (N/8);
    #pragma unroll 4
    for (int t2 = 0; t2 < N/8; t2 += 2) {      // 2 x ulonglong2 per iter
        ulonglong2 ka = kp[base + t2];
        ulonglong2 kb = kp[base + t2 + 1];
        c0 += (ka.x > my);  c1 += (ka.y > my);
        c2 += (kb.x > my);  c3 += (kb.y > my);
        d0 += (ka.x > thr); d1 += (ka.y > thr);
        d2 += (kb.x > thr); d3 += (kb.y > thr);
    }
    partial[tid]  = (c0 + c1) + (c2 + c3);
    partial2[tid] = (d0 + d1) + (d2 + d3);
    __syncthreads();
    if (tid < 64) {
        int rank = partial[tid] + partial[tid+64] + partial[tid+128] + partial[tid+192];
        int kc   = partial2[tid] + partial2[tid+64] + partial2[tid+128] + partial2[tid+192];
        unsigned long long km = keys[m0 + tid];
        unsigned int k32 = (unsigned int)(km >> 12);
        unsigned int u = (k32 & 0x80000000u) ? (k32 & 0x7fffffffu) : ~k32;
        ws[OFF_SC + b*N + rank] = __uint_as_float(u);
        ((int*)(ws + OFF_SIDX))[b*N + rank] = m0 + tid;
        ((int*)(ws + OFF_KN))[b*N + m0 + tid] = kc;
    }
}

// ------------------------------------------------------------------
// K3: 256 thr, two-level scan. Wave w: 16-step local prefix of
// [g[m,i] ; c_m*g[m,i]] (64 channels); segment offsets recombine.
__global__ __launch_bounds__(256) void k_prefix(float* __restrict__ ws)
{
    __shared__ int   sidx[64];
    __shared__ float scv[64];
    __shared__ float pl_lds[64*64];      // [k][ch] (16 KB)
    __shared__ float wtot[4*64];
    __shared__ float segoff[4*64];
    const int tid = threadIdx.x;
    const int blk = blockIdx.x;          // b*NT + t
    const int b = blk / NT, t = blk % NT;
    const int k0 = t * 64;
    if (tid < 64) {
        sidx[tid] = ((const int*)(ws + OFF_SIDX))[b*N + k0 + tid];
        scv[tid]  = ws[OFF_SC + b*N + k0 + tid];
    }
    __syncthreads();
    const int w   = tid >> 6;            // k-segment
    const int ch  = tid & 63;
    const int chm = ch & 31;
    const bool isCG = ch >= 32;
    const float* gx = ws + OFF_GX + (size_t)b*N*CI;
    float acc = 0.f;
    #pragma unroll
    for (int kk = 0; kk < 16; kk++) {
        int k = w*16 + kk;
        int m = sidx[k];                               // wave-uniform
        float gval = gx[(size_t)m*CI + chm];           // 128B gather, 2-way bcast
        float v = isCG ? gval * scv[k] : gval;
        pl_lds[k*64 + ch] = acc;
        acc += v;
    }
    wtot[w*64 + ch] = acc;
    __syncthreads();
    if (tid < 64) {
        float s = 0.f;
        #pragma unroll
        for (int ww = 0; ww < 4; ww++) { segoff[ww*64 + tid] = s; s += wtot[ww*64 + tid]; }
        ws[OFF_TOT + ((size_t)b*NT + t)*64 + tid] = s;     // tile total
    }
    __syncthreads();
    float* pl = ws + OFF_PLOC + ((size_t)b*N + k0)*64;
    #pragma unroll
    for (int r4 = 0; r4 < 16; r4++) {
        int r = (tid >> 6) + r4*4;
        pl[(size_t)r*64 + ch] = pl_lds[r*64 + ch] + segoff[(r >> 4)*64 + ch];
    }
}

// ------------------------------------------------------------------
// K4: per (b,tile): y via KN lookup (no binsearch) + prefix; wy = W·y + W_b
// stored to OFF_WY; per-block BN partials (f32, no atomics).
__global__ __launch_bounds__(256) void k_stats(
    const float* __restrict__ W_w, const float* __restrict__ W_b,
    float* __restrict__ ws)
{
    __shared__ float offs_lds[(NT+1)*64];    // 9472 B
    __shared__ float y_lds[64*33];           // 8448 B
    __shared__ float Wl[C*CI];               // 8192 B
    __shared__ float Wbl[C];
    const int tid = threadIdx.x;
    const int blk = blockIdx.x;
    const int b = blk / NT, tile = blk % NT;

    for (int i = tid; i < C*CI; i += 256) Wl[i] = W_w[i];
    if (tid < C) Wbl[tid] = W_b[tid];
    {   // stage tile totals (coalesced)
        const float* tot = ws + OFF_TOT + (size_t)b*NT*64;
        for (int i = tid; i < NT*64; i += 256) offs_lds[i] = tot[i];
    }
    __syncthreads();
    if (tid < 64) {   // in-LDS exclusive scan over tiles (per channel)
        float acc = 0.f;
        #pragma unroll 4
        for (int t = 0; t < NT; t++) {
            float v = offs_lds[t*64 + tid];
            offs_lds[t*64 + tid] = acc;
            acc += v;
        }
        offs_lds[NT*64 + tid] = acc;
    }
    __syncthreads();

    const int p = tid & 63, wv = tid >> 6;
    const int n = tile*64 + p;
    const float an = ws[OFF_A + b*N + n];
    const int k = ((const int*)(ws + OFF_KN))[b*N + n];
    const int kt = k >> 6;
    const float* pl = ws + OFF_PLOC + ((size_t)b*N + k)*64;
    const float inv_n = 1.0f / (float)N;
    #pragma unroll
    for (int q = 0; q < 8; q++) {
        int i = wv*8 + q;
        float plg = (k < N) ? pl[i]      : 0.f;
        float plc = (k < N) ? pl[i + 32] : 0.f;
        float Pg = offs_lds[kt*64 + i]      + plg;
        float Pc = offs_lds[kt*64 + i + 32] + plc;
        y_lds[p*33 + i] = inv_n * (an * Pg + Pc);
    }
    __syncthreads();

    // hoist y[p][0..31] to registers (stride-33 -> conflict-free)
    float yv[CI];
    #pragma unroll
    for (int i = 0; i < CI; i++) yv[i] = y_lds[p*33 + i];

    const int lane = tid & 63;
    float* part = ws + OFF_PART + (size_t)blk*128;
    float* wyb  = ws + OFF_WY + (size_t)b*C*N + n;
    #pragma unroll
    for (int q = 0; q < 16; q++) {
        int c = wv*16 + q;                             // wave-uniform
        float wyv = Wbl[c];
        #pragma unroll
        for (int i4 = 0; i4 < CI; i4 += 4) {
            float4 w4 = *(const float4*)(Wl + c*CI + i4);   // b128 broadcast
            wyv += w4.x*yv[i4] + w4.y*yv[i4+1] + w4.z*yv[i4+2] + w4.w*yv[i4+3];
        }
        wyb[(size_t)c*N] = wyv;                        // coalesced over lanes
        float s = wyv, sq = wyv * wyv;
        #pragma unroll
        for (int off = 32; off >= 1; off >>= 1) {
            s  += __shfl_xor(s,  off, 64);
            sq += __shfl_xor(sq, off, 64);
        }
        if (lane == 0) { part[c] = s; part[64 + c] = sq; }
    }
}

// ------------------------------------------------------------------
// K5: per-block redundant reduce of partials -> scale/shift, then stream
// out = wy*scale + shift + x. 288 blocks x 4 float4/thread.
__global__ __launch_bounds__(256) void k_final(
    const float* __restrict__ x,
    const float* __restrict__ bn_g, const float* __restrict__ bn_b,
    const float* __restrict__ ws, float* __restrict__ out)
{
    __shared__ double red[256];
    __shared__ float ssc[128];               // scale[64], shift[64]
    const int tid = threadIdx.x;
    {   // redundant per-block reduce (L2-resident, coalesced)
        const float* part = ws + OFF_PART;
        const int ch = tid & 127, half = tid >> 7;
        double acc = 0.0;
        #pragma unroll 8
        for (int k2 = 0; k2 < NTILES/2; k2++)
            acc += (double)part[(size_t)(half*(NTILES/2) + k2)*128 + ch];
        red[tid] = acc;
    }
    __syncthreads();
    if (tid < 64) {
        double ssum = red[tid]      + red[tid + 128];
        double ssq  = red[tid + 64] + red[tid + 192];
        double mean = ssum / (double)NTOT;
        double var  = ssq / (double)NTOT - mean*mean;
        float rs  = (float)(1.0 / sqrt(var + BN_EPS));
        float scl = bn_g[tid] * rs;
        ssc[tid]      = scl;
        ssc[64 + tid] = bn_b[tid] - (float)mean * scl;
    }
    __syncthreads();
    const float4* wy4 = (const float4*)(ws + OFF_WY);
    const float4* x4p = (const float4*)x;
    float4*       o4p = (float4*)out;
    #pragma unroll
    for (int j = 0; j < 4; j++) {
        const int idx = blockIdx.x*1024 + j*256 + tid;     // float4 index
        const float4 w4 = wy4[idx];
        const float4 xv = x4p[idx];
        const int c = ((idx*4) / N) & 63;                  // row-uniform (N%4==0)
        const float s = ssc[c], sh = ssc[64 + c];
        float4 o;
        o.x = w4.x*s + sh + xv.x;
        o.y = w4.y*s + sh + xv.y;
        o.z = w4.z*s + sh + xv.z;
        o.w = w4.w*s + sh + xv.w;
        o4p[idx] = o;
    }
}

// ------------------------------------------------------------------
extern "C" void kernel_launch(void* const* d_in, const int* in_sizes, int n_in,
                              void* d_out, int out_size, void* d_ws, size_t ws_size,
                              hipStream_t stream)
{
    const float* x     = (const float*)d_in[0];
    const float* g_w   = (const float*)d_in[1];
    const float* g_b   = (const float*)d_in[2];
    const float* th_w  = (const float*)d_in[3];
    const float* th_b  = (const float*)d_in[4];
    const float* ph_w  = (const float*)d_in[5];
    const float* ph_b  = (const float*)d_in[6];
    const float* cp_wt = (const float*)d_in[7];
    const float* cp_wp = (const float*)d_in[8];
    const float* W_w   = (const float*)d_in[9];
    const float* W_b   = (const float*)d_in[10];
    const float* bn_g  = (const float*)d_in[11];
    const float* bn_b  = (const float*)d_in[12];
    float* ws  = (float*)d_ws;
    float* out = (float*)d_out;

    hipLaunchKernelGGL(k_proj,   dim3(NTILES), dim3(256), 0, stream,
                       x, g_w, g_b, th_w, th_b, ph_w, ph_b, cp_wt, cp_wp, ws);
    hipLaunchKernelGGL(k_rank,   dim3(NTILES), dim3(256), 0, stream, ws);
    hipLaunchKernelGGL(k_prefix, dim3(NTILES), dim3(256), 0, stream, ws);
    hipLaunchKernelGGL(k_stats,  dim3(NTILES), dim3(256), 0, stream, W_w, W_b, ws);
    hipLaunchKernelGGL(k_final,  dim3(NTILES), dim3(256), 0, stream,
                       x, bn_g, bn_b, ws, out);
}

// Round 19
// 61.655 us; speedup vs baseline: 2.3929x; 1.0394x over previous
//
#include <hip/hip_runtime.h>
#include <math.h>

#define B 8
#define C 64
#define CI 32
#define N 2304        // 48*48
#define NT 36         // tiles of 64
#define NTILES (B*NT) // 288
#define NTOT (B*N)    // 18432
#define BN_EPS 1e-5

// ---- workspace layout (float offsets) ----
#define OFF_GX   0                      // [B][N][CI] g_x
#define OFF_A    (OFF_GX + B*N*CI)      // [B][N]
#define OFF_C    (OFF_A + B*N)          // [B][N]
#define OFF_SC   (OFF_C + B*N)          // [B][N] sorted desc
#define OFF_SIDX (OFF_SC + B*N)         // [B][N] int
#define OFF_KN   (OFF_SIDX + B*N)       // [B][N] int: k(n)=#{j: c_j > -a_n}
#define OFF_PLOC (OFF_KN + B*N)         // [B][N][64] excl. in-tile prefix (g | c*g)
#define OFF_TOT  (OFF_PLOC + B*N*64)    // [B][NT][64] tile totals
#define OFF_PART (OFF_TOT + B*NT*64)    // [NTILES][128] f32 per-tile partials
#define OFF_WY   (OFF_PART + NTILES*128) // [B][C][N] wy (pre-BN)

// ------------------------------------------------------------------
// K1: 288 blocks x 256 thr. Thread (p, wv): position, channel-octet.
// gw staged in LDS (verified faster than per-lane same-address global
// loads -- round 17 A/B).
__global__ __launch_bounds__(256) void k_proj(
    const float* __restrict__ x,
    const float* __restrict__ g_w, const float* __restrict__ g_b,
    const float* __restrict__ th_w, const float* __restrict__ th_b,
    const float* __restrict__ ph_w, const float* __restrict__ ph_b,
    const float* __restrict__ cp_wt, const float* __restrict__ cp_wp,
    float* __restrict__ ws)
{
    __shared__ float gw[CI*C];      // [i][c] (c contiguous)
    __shared__ float tw[C], pw[C];
    __shared__ float gb[CI];
    __shared__ float tpb[2];
    const int tid = threadIdx.x;
    const int blk = blockIdx.x;     // b*NT + t
    const int b  = blk / NT;
    const int n0 = (blk % NT) * 64;

    for (int i = tid; i < CI*C; i += 256) gw[i] = g_w[i];
    if (tid < C) {
        float s = 0.f;
        for (int i = 0; i < CI; i++) s += cp_wt[i] * th_w[i*C + tid];
        tw[tid] = s;
    } else if (tid < 2*C) {
        int c = tid - C; float s = 0.f;
        for (int i = 0; i < CI; i++) s += cp_wp[i] * ph_w[i*C + c];
        pw[c] = s;
    } else if (tid < 2*C + CI) {
        gb[tid - 2*C] = g_b[tid - 2*C];
    } else if (tid == 2*C + CI) {
        float s = 0.f; for (int i = 0; i < CI; i++) s += cp_wt[i]*th_b[i]; tpb[0] = s;
    } else if (tid == 2*C + CI + 1) {
        float s = 0.f; for (int i = 0; i < CI; i++) s += cp_wp[i]*ph_b[i]; tpb[1] = s;
    }
    __syncthreads();

    const int p = tid & 63, wv = tid >> 6;
    const int n = n0 + p;
    const int ch0 = wv*8;
    const float* xb = x + (size_t)b*C*N + n;
    float accg[8];
    #pragma unroll
    for (int j = 0; j < 8; j++) accg[j] = 0.f;
    float aa = 0.f, cc = 0.f;
    #pragma unroll 4
    for (int c4 = 0; c4 < C; c4 += 4) {
        float xv0 = xb[(size_t)(c4+0)*N];          // coalesced over p
        float xv1 = xb[(size_t)(c4+1)*N];
        float xv2 = xb[(size_t)(c4+2)*N];
        float xv3 = xb[(size_t)(c4+3)*N];
        if (wv == 0) {                              // wave-uniform branch
            float4 t4 = *(const float4*)(tw + c4);
            aa += t4.x*xv0 + t4.y*xv1 + t4.z*xv2 + t4.w*xv3;
        } else if (wv == 1) {
            float4 p4 = *(const float4*)(pw + c4);
            cc += p4.x*xv0 + p4.y*xv1 + p4.z*xv2 + p4.w*xv3;
        }
        #pragma unroll
        for (int j = 0; j < 8; j++) {
            float4 g4 = *(const float4*)(gw + (ch0+j)*C + c4);   // b128 broadcast
            accg[j] += g4.x*xv0 + g4.y*xv1 + g4.z*xv2 + g4.w*xv3;
        }
    }
    #pragma unroll
    for (int j = 0; j < 8; j++) accg[j] += gb[ch0 + j];
    float* gxp = ws + OFF_GX + ((size_t)(b*N + n))*CI + ch0;
    *(float4*)(gxp)     = make_float4(accg[0], accg[1], accg[2], accg[3]);
    *(float4*)(gxp + 4) = make_float4(accg[4], accg[5], accg[6], accg[7]);
    if (wv == 0) ws[OFF_A + b*N + n] = aa + tpb[0];
    else if (wv == 1) ws[OFF_C + b*N + n] = cc + tpb[1];
}

// ------------------------------------------------------------------
// K2: rank-by-counting with u64 keys + k-count. NOW 512 thr / 8 waves:
// each wave scans N/8 of the keys (same total LDS traffic, 2x waves/SIMD
// for latency hiding). key/thr semantics unchanged (verified r11/r18).
__global__ __launch_bounds__(512) void k_rank(float* __restrict__ ws)
{
    __shared__ __align__(16) unsigned long long keys[N];   // 18 KB
    __shared__ int partial[512];
    __shared__ int partial2[512];
    __shared__ float av[64];
    const int tid = threadIdx.x;
    const int blk = blockIdx.x;      // b*NT + mtile
    const int b  = blk / NT;
    const int m0 = (blk % NT) * 64;
    const float* cb = ws + OFF_C + (size_t)b*N;
    for (int i = tid; i < N; i += 512) {
        unsigned int u = __float_as_uint(cb[i]);
        unsigned int k32 = (u & 0x80000000u) ? ~u : (u | 0x80000000u);
        keys[i] = ((unsigned long long)k32 << 12) | (unsigned long long)(4095 - i);
    }
    if (tid < 64) av[tid] = ws[OFF_A + b*N + m0 + tid];
    __syncthreads();
    const int p = tid & 63;
    const int wv = tid >> 6;                   // wave id = j-eighth (0..7)
    const unsigned long long my = keys[m0 + p];
    unsigned int ua  = __float_as_uint(-av[p]);
    unsigned int t32 = (ua & 0x80000000u) ? ~ua : (ua | 0x80000000u);
    const unsigned long long thr = ((unsigned long long)t32 << 12) | 4095ull;
    const ulonglong2* kp = (const ulonglong2*)keys;
    int c0=0,c1=0,c2=0,c3=0, d0=0,d1=0,d2=0,d3=0;
    const int base = wv * (N/16);              // N/2 ulonglong2 / 8 waves
    #pragma unroll 4
    for (int t2 = 0; t2 < N/16; t2 += 2) {     // 2 x ulonglong2 per iter
        ulonglong2 ka = kp[base + t2];
        ulonglong2 kb = kp[base + t2 + 1];
        c0 += (ka.x > my);  c1 += (ka.y > my);
        c2 += (kb.x > my);  c3 += (kb.y > my);
        d0 += (ka.x > thr); d1 += (ka.y > thr);
        d2 += (kb.x > thr); d3 += (kb.y > thr);
    }
    partial[tid]  = (c0 + c1) + (c2 + c3);
    partial2[tid] = (d0 + d1) + (d2 + d3);
    __syncthreads();
    if (tid < 64) {
        int rank = 0, kc = 0;
        #pragma unroll
        for (int w = 0; w < 8; w++) {
            rank += partial[tid + 64*w];
            kc   += partial2[tid + 64*w];
        }
        unsigned long long km = keys[m0 + tid];
        unsigned int k32 = (unsigned int)(km >> 12);
        unsigned int u = (k32 & 0x80000000u) ? (k32 & 0x7fffffffu) : ~k32;
        ws[OFF_SC + b*N + rank] = __uint_as_float(u);
        ((int*)(ws + OFF_SIDX))[b*N + rank] = m0 + tid;
        ((int*)(ws + OFF_KN))[b*N + m0 + tid] = kc;
    }
}

// ------------------------------------------------------------------
// K3: 256 thr, two-level scan. Wave w: 16-step local prefix of
// [g[m,i] ; c_m*g[m,i]] (64 channels); segment offsets recombine.
__global__ __launch_bounds__(256) void k_prefix(float* __restrict__ ws)
{
    __shared__ int   sidx[64];
    __shared__ float scv[64];
    __shared__ float pl_lds[64*64];      // [k][ch] (16 KB)
    __shared__ float wtot[4*64];
    __shared__ float segoff[4*64];
    const int tid = threadIdx.x;
    const int blk = blockIdx.x;          // b*NT + t
    const int b = blk / NT, t = blk % NT;
    const int k0 = t * 64;
    if (tid < 64) {
        sidx[tid] = ((const int*)(ws + OFF_SIDX))[b*N + k0 + tid];
        scv[tid]  = ws[OFF_SC + b*N + k0 + tid];
    }
    __syncthreads();
    const int w   = tid >> 6;            // k-segment
    const int ch  = tid & 63;
    const int chm = ch & 31;
    const bool isCG = ch >= 32;
    const float* gx = ws + OFF_GX + (size_t)b*N*CI;
    float acc = 0.f;
    #pragma unroll
    for (int kk = 0; kk < 16; kk++) {
        int k = w*16 + kk;
        int m = sidx[k];                               // wave-uniform
        float gval = gx[(size_t)m*CI + chm];           // 128B gather, 2-way bcast
        float v = isCG ? gval * scv[k] : gval;
        pl_lds[k*64 + ch] = acc;
        acc += v;
    }
    wtot[w*64 + ch] = acc;
    __syncthreads();
    if (tid < 64) {
        float s = 0.f;
        #pragma unroll
        for (int ww = 0; ww < 4; ww++) { segoff[ww*64 + tid] = s; s += wtot[ww*64 + tid]; }
        ws[OFF_TOT + ((size_t)b*NT + t)*64 + tid] = s;     // tile total
    }
    __syncthreads();
    float* pl = ws + OFF_PLOC + ((size_t)b*N + k0)*64;
    #pragma unroll
    for (int r4 = 0; r4 < 16; r4++) {
        int r = (tid >> 6) + r4*4;
        pl[(size_t)r*64 + ch] = pl_lds[r*64 + ch] + segoff[(r >> 4)*64 + ch];
    }
}

// ------------------------------------------------------------------
// K4: per (b,tile): y via KN lookup (no binsearch) + prefix; wy = W·y + W_b
// stored to OFF_WY; per-block BN partials (f32, no atomics).
__global__ __launch_bounds__(256) void k_stats(
    const float* __restrict__ W_w, const float* __restrict__ W_b,
    float* __restrict__ ws)
{
    __shared__ float offs_lds[(NT+1)*64];    // 9472 B
    __shared__ float y_lds[64*33];           // 8448 B
    __shared__ float Wl[C*CI];               // 8192 B
    __shared__ float Wbl[C];
    const int tid = threadIdx.x;
    const int blk = blockIdx.x;
    const int b = blk / NT, tile = blk % NT;

    for (int i = tid; i < C*CI; i += 256) Wl[i] = W_w[i];
    if (tid < C) Wbl[tid] = W_b[tid];
    {   // stage tile totals (coalesced)
        const float* tot = ws + OFF_TOT + (size_t)b*NT*64;
        for (int i = tid; i < NT*64; i += 256) offs_lds[i] = tot[i];
    }
    __syncthreads();
    if (tid < 64) {   // in-LDS exclusive scan over tiles (per channel)
        float acc = 0.f;
        #pragma unroll 4
        for (int t = 0; t < NT; t++) {
            float v = offs_lds[t*64 + tid];
            offs_lds[t*64 + tid] = acc;
            acc += v;
        }
        offs_lds[NT*64 + tid] = acc;
    }
    __syncthreads();

    const int p = tid & 63, wv = tid >> 6;
    const int n = tile*64 + p;
    const float an = ws[OFF_A + b*N + n];
    const int k = ((const int*)(ws + OFF_KN))[b*N + n];
    const int kt = k >> 6;
    const float* pl = ws + OFF_PLOC + ((size_t)b*N + k)*64;
    const float inv_n = 1.0f / (float)N;
    #pragma unroll
    for (int q = 0; q < 8; q++) {
        int i = wv*8 + q;
        float plg = (k < N) ? pl[i]      : 0.f;
        float plc = (k < N) ? pl[i + 32] : 0.f;
        float Pg = offs_lds[kt*64 + i]      + plg;
        float Pc = offs_lds[kt*64 + i + 32] + plc;
        y_lds[p*33 + i] = inv_n * (an * Pg + Pc);
    }
    __syncthreads();

    // hoist y[p][0..31] to registers (stride-33 -> conflict-free)
    float yv[CI];
    #pragma unroll
    for (int i = 0; i < CI; i++) yv[i] = y_lds[p*33 + i];

    const int lane = tid & 63;
    float* part = ws + OFF_PART + (size_t)blk*128;
    float* wyb  = ws + OFF_WY + (size_t)b*C*N + n;
    #pragma unroll
    for (int q = 0; q < 16; q++) {
        int c = wv*16 + q;                             // wave-uniform
        float wyv = Wbl[c];
        #pragma unroll
        for (int i4 = 0; i4 < CI; i4 += 4) {
            float4 w4 = *(const float4*)(Wl + c*CI + i4);   // b128 broadcast
            wyv += w4.x*yv[i4] + w4.y*yv[i4+1] + w4.z*yv[i4+2] + w4.w*yv[i4+3];
        }
        wyb[(size_t)c*N] = wyv;                        // coalesced over lanes
        float s = wyv, sq = wyv * wyv;
        #pragma unroll
        for (int off = 32; off >= 1; off >>= 1) {
            s  += __shfl_xor(s,  off, 64);
            sq += __shfl_xor(sq, off, 64);
        }
        if (lane == 0) { part[c] = s; part[64 + c] = sq; }
    }
}

// ------------------------------------------------------------------
// K5: per-block redundant reduce of partials -> scale/shift, then stream
// out = wy*scale + shift + x. 288 blocks x 4 float4/thread.
__global__ __launch_bounds__(256) void k_final(
    const float* __restrict__ x,
    const float* __restrict__ bn_g, const float* __restrict__ bn_b,
    const float* __restrict__ ws, float* __restrict__ out)
{
    __shared__ double red[256];
    __shared__ float ssc[128];               // scale[64], shift[64]
    const int tid = threadIdx.x;
    {   // redundant per-block reduce (L2-resident, coalesced)
        const float* part = ws + OFF_PART;
        const int ch = tid & 127, half = tid >> 7;
        double acc = 0.0;
        #pragma unroll 8
        for (int k2 = 0; k2 < NTILES/2; k2++)
            acc += (double)part[(size_t)(half*(NTILES/2) + k2)*128 + ch];
        red[tid] = acc;
    }
    __syncthreads();
    if (tid < 64) {
        double ssum = red[tid]      + red[tid + 128];
        double ssq  = red[tid + 64] + red[tid + 192];
        double mean = ssum / (double)NTOT;
        double var  = ssq / (double)NTOT - mean*mean;
        float rs  = (float)(1.0 / sqrt(var + BN_EPS));
        float scl = bn_g[tid] * rs;
        ssc[tid]      = scl;
        ssc[64 + tid] = bn_b[tid] - (float)mean * scl;
    }
    __syncthreads();
    const float4* wy4 = (const float4*)(ws + OFF_WY);
    const float4* x4p = (const float4*)x;
    float4*       o4p = (float4*)out;
    #pragma unroll
    for (int j = 0; j < 4; j++) {
        const int idx = blockIdx.x*1024 + j*256 + tid;     // float4 index
        const float4 w4 = wy4[idx];
        const float4 xv = x4p[idx];
        const int c = ((idx*4) / N) & 63;                  // row-uniform (N%4==0)
        const float s = ssc[c], sh = ssc[64 + c];
        float4 o;
        o.x = w4.x*s + sh + xv.x;
        o.y = w4.y*s + sh + xv.y;
        o.z = w4.z*s + sh + xv.z;
        o.w = w4.w*s + sh + xv.w;
        o4p[idx] = o;
    }
}

// ------------------------------------------------------------------
extern "C" void kernel_launch(void* const* d_in, const int* in_sizes, int n_in,
                              void* d_out, int out_size, void* d_ws, size_t ws_size,
                              hipStream_t stream)
{
    const float* x     = (const float*)d_in[0];
    const float* g_w   = (const float*)d_in[1];
    const float* g_b   = (const float*)d_in[2];
    const float* th_w  = (const float*)d_in[3];
    const float* th_b  = (const float*)d_in[4];
    const float* ph_w  = (const float*)d_in[5];
    const float* ph_b  = (const float*)d_in[6];
    const float* cp_wt = (const float*)d_in[7];
    const float* cp_wp = (const float*)d_in[8];
    const float* W_w   = (const float*)d_in[9];
    const float* W_b   = (const float*)d_in[10];
    const float* bn_g  = (const float*)d_in[11];
    const float* bn_b  = (const float*)d_in[12];
    float* ws  = (float*)d_ws;
    float* out = (float*)d_out;

    hipLaunchKernelGGL(k_proj,   dim3(NTILES), dim3(256), 0, stream,
                       x, g_w, g_b, th_w, th_b, ph_w, ph_b, cp_wt, cp_wp, ws);
    hipLaunchKernelGGL(k_rank,   dim3(NTILES), dim3(512), 0, stream, ws);
    hipLaunchKernelGGL(k_prefix, dim3(NTILES), dim3(256), 0, stream, ws);
    hipLaunchKernelGGL(k_stats,  dim3(NTILES), dim3(256), 0, stream, W_w, W_b, ws);
    hipLaunchKernelGGL(k_final,  dim3(NTILES), dim3(256), 0, stream,
                       x, bn_g, bn_b, ws, out);
}

// Round 20
// 54.671 us; speedup vs baseline: 2.6985x; 1.1277x over previous
//
#include <hip/hip_runtime.h>
#include <math.h>

#define B 8
#define C 64
#define CI 32
#define N 2304        // 48*48
#define NT 36         // tiles of 64
#define NTILES (B*NT) // 288
#define NTOT (B*N)    // 18432
#define BN_EPS 1e-5

// ---- workspace layout (float offsets) ----
#define OFF_GX   0                      // [B][N][CI] g_x
#define OFF_A    (OFF_GX + B*N*CI)      // [B][N]
#define OFF_C    (OFF_A + B*N)          // [B][N]
#define OFF_SC   (OFF_C + B*N)          // [B][N] sorted desc
#define OFF_SIDX (OFF_SC + B*N)         // [B][N] int
#define OFF_KN   (OFF_SIDX + B*N)       // [B][N] int: k(n)=#{j: c_j > -a_n}
#define OFF_PLOC (OFF_KN + B*N)         // [B][N][64] excl. in-tile prefix (g | c*g)
#define OFF_TOT  (OFF_PLOC + B*N*64)    // [B][NT][64] tile totals
#define OFF_PART (OFF_TOT + B*NT*64)    // [NTILES][128] f32 per-tile partials
#define OFF_WY   (OFF_PART + NTILES*128) // [B][C][N] wy (pre-BN)

// ------------------------------------------------------------------
// K1: 288 blocks x 512 thr (8 waves). Thread (p, wv): position, 4 channels.
// gw staged in LDS (verified faster than per-lane same-address global loads,
// round-17 A/B). 512-thr TLP split validated on k_rank (round 19).
__global__ __launch_bounds__(512) void k_proj(
    const float* __restrict__ x,
    const float* __restrict__ g_w, const float* __restrict__ g_b,
    const float* __restrict__ th_w, const float* __restrict__ th_b,
    const float* __restrict__ ph_w, const float* __restrict__ ph_b,
    const float* __restrict__ cp_wt, const float* __restrict__ cp_wp,
    float* __restrict__ ws)
{
    __shared__ float gw[CI*C];      // [i][c] (c contiguous)
    __shared__ float tw[C], pw[C];
    __shared__ float gb[CI];
    __shared__ float tpb[2];
    const int tid = threadIdx.x;
    const int blk = blockIdx.x;     // b*NT + t
    const int b  = blk / NT;
    const int n0 = (blk % NT) * 64;

    for (int i = tid; i < CI*C; i += 512) gw[i] = g_w[i];
    if (tid < C) {
        float s = 0.f;
        for (int i = 0; i < CI; i++) s += cp_wt[i] * th_w[i*C + tid];
        tw[tid] = s;
    } else if (tid < 2*C) {
        int c = tid - C; float s = 0.f;
        for (int i = 0; i < CI; i++) s += cp_wp[i] * ph_w[i*C + c];
        pw[c] = s;
    } else if (tid < 2*C + CI) {
        gb[tid - 2*C] = g_b[tid - 2*C];
    } else if (tid == 2*C + CI) {
        float s = 0.f; for (int i = 0; i < CI; i++) s += cp_wt[i]*th_b[i]; tpb[0] = s;
    } else if (tid == 2*C + CI + 1) {
        float s = 0.f; for (int i = 0; i < CI; i++) s += cp_wp[i]*ph_b[i]; tpb[1] = s;
    }
    __syncthreads();

    const int p = tid & 63, wv = tid >> 6;     // wv 0..7
    const int n = n0 + p;
    const int ch0 = wv*4;                      // 8 waves x 4 channels = CI
    const float* xb = x + (size_t)b*C*N + n;
    float accg[4];
    #pragma unroll
    for (int j = 0; j < 4; j++) accg[j] = 0.f;
    float aa = 0.f, cc = 0.f;
    #pragma unroll 4
    for (int c4 = 0; c4 < C; c4 += 4) {
        float xv0 = xb[(size_t)(c4+0)*N];          // coalesced over p
        float xv1 = xb[(size_t)(c4+1)*N];
        float xv2 = xb[(size_t)(c4+2)*N];
        float xv3 = xb[(size_t)(c4+3)*N];
        if (wv == 0) {                              // wave-uniform branch
            float4 t4 = *(const float4*)(tw + c4);
            aa += t4.x*xv0 + t4.y*xv1 + t4.z*xv2 + t4.w*xv3;
        } else if (wv == 1) {
            float4 p4 = *(const float4*)(pw + c4);
            cc += p4.x*xv0 + p4.y*xv1 + p4.z*xv2 + p4.w*xv3;
        }
        #pragma unroll
        for (int j = 0; j < 4; j++) {
            float4 g4 = *(const float4*)(gw + (ch0+j)*C + c4);   // b128 broadcast
            accg[j] += g4.x*xv0 + g4.y*xv1 + g4.z*xv2 + g4.w*xv3;
        }
    }
    #pragma unroll
    for (int j = 0; j < 4; j++) accg[j] += gb[ch0 + j];
    float* gxp = ws + OFF_GX + ((size_t)(b*N + n))*CI + ch0;
    *(float4*)(gxp) = make_float4(accg[0], accg[1], accg[2], accg[3]);
    if (wv == 0) ws[OFF_A + b*N + n] = aa + tpb[0];
    else if (wv == 1) ws[OFF_C + b*N + n] = cc + tpb[1];
}

// ------------------------------------------------------------------
// K2: rank-by-counting with u64 keys + k-count. 512 thr / 8 waves, each
// scans N/8 of the keys (round-19 verified: 64.0 -> 61.7).
__global__ __launch_bounds__(512) void k_rank(float* __restrict__ ws)
{
    __shared__ __align__(16) unsigned long long keys[N];   // 18 KB
    __shared__ int partial[512];
    __shared__ int partial2[512];
    __shared__ float av[64];
    const int tid = threadIdx.x;
    const int blk = blockIdx.x;      // b*NT + mtile
    const int b  = blk / NT;
    const int m0 = (blk % NT) * 64;
    const float* cb = ws + OFF_C + (size_t)b*N;
    for (int i = tid; i < N; i += 512) {
        unsigned int u = __float_as_uint(cb[i]);
        unsigned int k32 = (u & 0x80000000u) ? ~u : (u | 0x80000000u);
        keys[i] = ((unsigned long long)k32 << 12) | (unsigned long long)(4095 - i);
    }
    if (tid < 64) av[tid] = ws[OFF_A + b*N + m0 + tid];
    __syncthreads();
    const int p = tid & 63;
    const int wv = tid >> 6;                   // wave id = j-eighth (0..7)
    const unsigned long long my = keys[m0 + p];
    unsigned int ua  = __float_as_uint(-av[p]);
    unsigned int t32 = (ua & 0x80000000u) ? ~ua : (ua | 0x80000000u);
    const unsigned long long thr = ((unsigned long long)t32 << 12) | 4095ull;
    const ulonglong2* kp = (const ulonglong2*)keys;
    int c0=0,c1=0,c2=0,c3=0, d0=0,d1=0,d2=0,d3=0;
    const int base = wv * (N/16);              // N/2 ulonglong2 / 8 waves
    #pragma unroll 4
    for (int t2 = 0; t2 < N/16; t2 += 2) {     // 2 x ulonglong2 per iter
        ulonglong2 ka = kp[base + t2];
        ulonglong2 kb = kp[base + t2 + 1];
        c0 += (ka.x > my);  c1 += (ka.y > my);
        c2 += (kb.x > my);  c3 += (kb.y > my);
        d0 += (ka.x > thr); d1 += (ka.y > thr);
        d2 += (kb.x > thr); d3 += (kb.y > thr);
    }
    partial[tid]  = (c0 + c1) + (c2 + c3);
    partial2[tid] = (d0 + d1) + (d2 + d3);
    __syncthreads();
    if (tid < 64) {
        int rank = 0, kc = 0;
        #pragma unroll
        for (int w = 0; w < 8; w++) {
            rank += partial[tid + 64*w];
            kc   += partial2[tid + 64*w];
        }
        unsigned long long km = keys[m0 + tid];
        unsigned int k32 = (unsigned int)(km >> 12);
        unsigned int u = (k32 & 0x80000000u) ? (k32 & 0x7fffffffu) : ~k32;
        ws[OFF_SC + b*N + rank] = __uint_as_float(u);
        ((int*)(ws + OFF_SIDX))[b*N + rank] = m0 + tid;
        ((int*)(ws + OFF_KN))[b*N + m0 + tid] = kc;
    }
}

// ------------------------------------------------------------------
// K3: 512 thr, two-level scan. Wave w (0..7): 8-step local prefix of
// [g[m,i] ; c_m*g[m,i]] (64 channels); 8 segment offsets recombine.
__global__ __launch_bounds__(512) void k_prefix(float* __restrict__ ws)
{
    __shared__ int   sidx[64];
    __shared__ float scv[64];
    __shared__ float pl_lds[64*64];      // [k][ch] (16 KB)
    __shared__ float wtot[8*64];
    __shared__ float segoff[8*64];
    const int tid = threadIdx.x;
    const int blk = blockIdx.x;          // b*NT + t
    const int b = blk / NT, t = blk % NT;
    const int k0 = t * 64;
    if (tid < 64) {
        sidx[tid] = ((const int*)(ws + OFF_SIDX))[b*N + k0 + tid];
        scv[tid]  = ws[OFF_SC + b*N + k0 + tid];
    }
    __syncthreads();
    const int w   = tid >> 6;            // k-segment (0..7)
    const int ch  = tid & 63;
    const int chm = ch & 31;
    const bool isCG = ch >= 32;
    const float* gx = ws + OFF_GX + (size_t)b*N*CI;
    float acc = 0.f;
    #pragma unroll
    for (int kk = 0; kk < 8; kk++) {
        int k = w*8 + kk;
        int m = sidx[k];                               // wave-uniform
        float gval = gx[(size_t)m*CI + chm];           // 128B gather, 2-way bcast
        float v = isCG ? gval * scv[k] : gval;
        pl_lds[k*64 + ch] = acc;
        acc += v;
    }
    wtot[w*64 + ch] = acc;
    __syncthreads();
    if (tid < 64) {
        float s = 0.f;
        #pragma unroll
        for (int ww = 0; ww < 8; ww++) { segoff[ww*64 + tid] = s; s += wtot[ww*64 + tid]; }
        ws[OFF_TOT + ((size_t)b*NT + t)*64 + tid] = s;     // tile total
    }
    __syncthreads();
    float* pl = ws + OFF_PLOC + ((size_t)b*N + k0)*64;
    #pragma unroll
    for (int r8 = 0; r8 < 8; r8++) {
        int r = w + r8*8;                                  // covers 0..63
        pl[(size_t)r*64 + ch] = pl_lds[r*64 + ch] + segoff[(r >> 3)*64 + ch];
    }
}

// ------------------------------------------------------------------
// K4: 512 thr. Per (b,tile): y via KN lookup + prefix; wy = W·y + W_b
// stored to OFF_WY; per-block BN partials (f32, no atomics).
__global__ __launch_bounds__(512) void k_stats(
    const float* __restrict__ W_w, const float* __restrict__ W_b,
    float* __restrict__ ws)
{
    __shared__ float offs_lds[(NT+1)*64];    // 9472 B
    __shared__ float y_lds[64*33];           // 8448 B
    __shared__ float Wl[C*CI];               // 8192 B
    __shared__ float Wbl[C];
    const int tid = threadIdx.x;
    const int blk = blockIdx.x;
    const int b = blk / NT, tile = blk % NT;

    for (int i = tid; i < C*CI; i += 512) Wl[i] = W_w[i];
    if (tid < C) Wbl[tid] = W_b[tid];
    {   // stage tile totals (coalesced)
        const float* tot = ws + OFF_TOT + (size_t)b*NT*64;
        for (int i = tid; i < NT*64; i += 512) offs_lds[i] = tot[i];
    }
    __syncthreads();
    if (tid < 64) {   // in-LDS exclusive scan over tiles (per channel)
        float acc = 0.f;
        #pragma unroll 4
        for (int t = 0; t < NT; t++) {
            float v = offs_lds[t*64 + tid];
            offs_lds[t*64 + tid] = acc;
            acc += v;
        }
        offs_lds[NT*64 + tid] = acc;
    }
    __syncthreads();

    const int p = tid & 63, wv = tid >> 6;     // wv 0..7
    const int n = tile*64 + p;
    const float an = ws[OFF_A + b*N + n];
    const int k = ((const int*)(ws + OFF_KN))[b*N + n];
    const int kt = k >> 6;
    const float* pl = ws + OFF_PLOC + ((size_t)b*N + k)*64;
    const float inv_n = 1.0f / (float)N;
    #pragma unroll
    for (int q = 0; q < 4; q++) {              // 8 waves x 4 = CI values
        int i = wv*4 + q;
        float plg = (k < N) ? pl[i]      : 0.f;
        float plc = (k < N) ? pl[i + 32] : 0.f;
        float Pg = offs_lds[kt*64 + i]      + plg;
        float Pc = offs_lds[kt*64 + i + 32] + plc;
        y_lds[p*33 + i] = inv_n * (an * Pg + Pc);
    }
    __syncthreads();

    // hoist y[p][0..31] to registers (stride-33 -> conflict-free)
    float yv[CI];
    #pragma unroll
    for (int i = 0; i < CI; i++) yv[i] = y_lds[p*33 + i];

    const int lane = tid & 63;
    float* part = ws + OFF_PART + (size_t)blk*128;
    float* wyb  = ws + OFF_WY + (size_t)b*C*N + n;
    #pragma unroll
    for (int q = 0; q < 8; q++) {              // 8 waves x 8 = C channels
        int c = wv*8 + q;                      // wave-uniform
        float wyv = Wbl[c];
        #pragma unroll
        for (int i4 = 0; i4 < CI; i4 += 4) {
            float4 w4 = *(const float4*)(Wl + c*CI + i4);   // b128 broadcast
            wyv += w4.x*yv[i4] + w4.y*yv[i4+1] + w4.z*yv[i4+2] + w4.w*yv[i4+3];
        }
        wyb[(size_t)c*N] = wyv;                // coalesced over lanes
        float s = wyv, sq = wyv * wyv;
        #pragma unroll
        for (int off = 32; off >= 1; off >>= 1) {
            s  += __shfl_xor(s,  off, 64);
            sq += __shfl_xor(sq, off, 64);
        }
        if (lane == 0) { part[c] = s; part[64 + c] = sq; }
    }
}

// ------------------------------------------------------------------
// K5: 512 thr. Per-block redundant reduce (4 quarters of 72 tiles) ->
// scale/shift, then stream out = wy*scale + shift + x (2 float4/thread).
__global__ __launch_bounds__(512) void k_final(
    const float* __restrict__ x,
    const float* __restrict__ bn_g, const float* __restrict__ bn_b,
    const float* __restrict__ ws, float* __restrict__ out)
{
    __shared__ double red[512];
    __shared__ float ssc[128];               // scale[64], shift[64]
    const int tid = threadIdx.x;
    {   // redundant per-block reduce (L2-resident, coalesced)
        const float* part = ws + OFF_PART;
        const int ch = tid & 127, qtr = tid >> 7;          // 4 quarters
        double acc = 0.0;
        #pragma unroll 8
        for (int k2 = 0; k2 < NTILES/4; k2++)
            acc += (double)part[(size_t)(qtr*(NTILES/4) + k2)*128 + ch];
        red[tid] = acc;
    }
    __syncthreads();
    if (tid < 64) {
        double ssum = red[tid]      + red[tid+128] + red[tid+256] + red[tid+384];
        double ssq  = red[tid+64]   + red[tid+192] + red[tid+320] + red[tid+448];
        double mean = ssum / (double)NTOT;
        double var  = ssq / (double)NTOT - mean*mean;
        float rs  = (float)(1.0 / sqrt(var + BN_EPS));
        float scl = bn_g[tid] * rs;
        ssc[tid]      = scl;
        ssc[64 + tid] = bn_b[tid] - (float)mean * scl;
    }
    __syncthreads();
    const float4* wy4 = (const float4*)(ws + OFF_WY);
    const float4* x4p = (const float4*)x;
    float4*       o4p = (float4*)out;
    #pragma unroll
    for (int j = 0; j < 2; j++) {
        const int idx = blockIdx.x*1024 + j*512 + tid;     // float4 index
        const float4 w4 = wy4[idx];
        const float4 xv = x4p[idx];
        const int c = ((idx*4) / N) & 63;                  // row-uniform (N%4==0)
        const float s = ssc[c], sh = ssc[64 + c];
        float4 o;
        o.x = w4.x*s + sh + xv.x;
        o.y = w4.y*s + sh + xv.y;
        o.z = w4.z*s + sh + xv.z;
        o.w = w4.w*s + sh + xv.w;
        o4p[idx] = o;
    }
}

// ------------------------------------------------------------------
extern "C" void kernel_launch(void* const* d_in, const int* in_sizes, int n_in,
                              void* d_out, int out_size, void* d_ws, size_t ws_size,
                              hipStream_t stream)
{
    const float* x     = (const float*)d_in[0];
    const float* g_w   = (const float*)d_in[1];
    const float* g_b   = (const float*)d_in[2];
    const float* th_w  = (const float*)d_in[3];
    const float* th_b  = (const float*)d_in[4];
    const float* ph_w  = (const float*)d_in[5];
    const float* ph_b  = (const float*)d_in[6];
    const float* cp_wt = (const float*)d_in[7];
    const float* cp_wp = (const float*)d_in[8];
    const float* W_w   = (const float*)d_in[9];
    const float* W_b   = (const float*)d_in[10];
    const float* bn_g  = (const float*)d_in[11];
    const float* bn_b  = (const float*)d_in[12];
    float* ws  = (float*)d_ws;
    float* out = (float*)d_out;

    hipLaunchKernelGGL(k_proj,   dim3(NTILES), dim3(512), 0, stream,
                       x, g_w, g_b, th_w, th_b, ph_w, ph_b, cp_wt, cp_wp, ws);
    hipLaunchKernelGGL(k_rank,   dim3(NTILES), dim3(512), 0, stream, ws);
    hipLaunchKernelGGL(k_prefix, dim3(NTILES), dim3(512), 0, stream, ws);
    hipLaunchKernelGGL(k_stats,  dim3(NTILES), dim3(512), 0, stream, W_w, W_b, ws);
    hipLaunchKernelGGL(k_final,  dim3(NTILES), dim3(512), 0, stream,
                       x, bn_g, bn_b, ws, out);
}